// Round 14
// baseline (430.304 us; speedup 1.0000x reference)
//
#include <hip/hip_runtime.h>

#define Bn 4
#define Nn 50000
#define En 1000000
#define FOUT 8

typedef unsigned int u32;
typedef unsigned short u16;
typedef __attribute__((ext_vector_type(8))) short bf16x8;
typedef __attribute__((ext_vector_type(4))) float f32x4;
typedef __attribute__((ext_vector_type(4))) int i32x4;

// ---- ws layout (bytes) ----
#define BLOB_BYTES 24576
#define W1T_OFF 0       // [64 q][32 k] bf16 (k padded 20->32)
#define W2T_OFF 4096    // [64 q][64 k] bf16
#define W3T_OFF 12288   // [64 c][64 k] bf16
#define B1_OFF 20480    // f32[64] sigma-permuted
#define B2_OFF 20736
#define B3_OFF 20992
#define BSUM_OFF 21248  // u32[256] in blob slack

#define CNT_OFF    24576
#define ROWPTR_OFF 224576
#define FILL_OFF   424704
#define PAIRS_OFF  624768                        // u32[En]: src | dst<<16  (Nn < 2^16)
#define MSG_OFF    4624768                       // bf16[En*8]
#define WS_NEEDED (MSG_OFF + (size_t)En * FOUT * 2)   // 20,624,768 B (round-6 proven)

__device__ __forceinline__ float fast_tanh(float x) {
    float e = __builtin_amdgcn_exp2f(x * 2.8853900817779268f);
    return 1.0f - 2.0f * __builtin_amdgcn_rcpf(e + 1.0f);
}
__device__ __forceinline__ u32 pkbf(float lo, float hi) {
    u32 r;
    asm("v_cvt_pk_bf16_f32 %0, %1, %2" : "=v"(r) : "v"(lo), "v"(hi));
    return r;
}
__device__ __forceinline__ float bflo(u32 u) { return __builtin_bit_cast(float, u << 16); }
__device__ __forceinline__ float bfhi(u32 u) { return __builtin_bit_cast(float, u & 0xffff0000u); }
__device__ __forceinline__ float bfu(u16 v) { return __builtin_bit_cast(float, (u32)v << 16); }
__device__ __forceinline__ u16 f2bf(float x) {
    u32 u = __builtin_bit_cast(u32, x);
    return (u16)((u + 0x7fff + ((u >> 16) & 1)) >> 16);
}
// sigma-permutation of MLP hidden channels (HW-verified rounds 4-13)
__device__ __forceinline__ int PERM_Q(int q) {
    int mi = q >> 4, g = (q >> 2) & 3, r = q & 3;
    return ((mi >> 1) << 5) | (g << 3) | ((mi & 1) << 2) | r;
}

__global__ void gno_init_weights(const float* __restrict__ W1, const float* __restrict__ b1,
                                 const float* __restrict__ W2, const float* __restrict__ b2,
                                 const float* __restrict__ W3, const float* __restrict__ b3,
                                 unsigned char* __restrict__ blob)
{
    int idx = blockIdx.x * 256 + threadIdx.x;
    if (idx < 2048) {
        int q = idx >> 5, k = idx & 31;
        float v = (k < 20) ? W1[k * 64 + PERM_Q(q)] : 0.0f;
        *(u16*)(blob + W1T_OFF + q * 64 + 2 * k) = f2bf(v);
    } else if (idx < 6144) {
        int j = idx - 2048, q = j >> 6, k = j & 63;
        *(u16*)(blob + W2T_OFF + q * 128 + 2 * k) = f2bf(W2[k * 64 + PERM_Q(q)]);
    } else if (idx < 10240) {
        int j = idx - 6144, c = j >> 6, k = j & 63;
        *(u16*)(blob + W3T_OFF + c * 128 + 2 * k) = f2bf(W3[k * 64 + c]);
    } else if (idx < 10304) { int q = idx - 10240; *(float*)(blob + B1_OFF + q * 4) = b1[PERM_Q(q)]; }
    else if (idx < 10368)   { int q = idx - 10304; *(float*)(blob + B2_OFF + q * 4) = b2[PERM_Q(q)]; }
    else if (idx < 10432)   { int c = idx - 10368; *(float*)(blob + B3_OFF + c * 4) = b3[c]; }
}

// ---- CSR build ----
__global__ void gno_hist(const int* __restrict__ neigh, u32* __restrict__ cnt) {
    const int e = blockIdx.x * 256 + threadIdx.x;
    if (e < En) atomicAdd(&cnt[neigh[e]], 1u);
}
__global__ __launch_bounds__(256) void gno_scan1(const u32* __restrict__ cnt,
                                                 u32* __restrict__ rowptr,
                                                 u32* __restrict__ bsum)
{
    __shared__ u32 wtot[4];
    const int tid = threadIdx.x, lane = tid & 63, w = tid >> 6;
    const int n = blockIdx.x * 256 + tid;
    const u32 c = (n < Nn) ? cnt[n] : 0u;
    u32 inc = c;
    #pragma unroll
    for (int off = 1; off < 64; off <<= 1) {
        u32 x = __shfl_up(inc, off, 64);
        if (lane >= off) inc += x;
    }
    if (lane == 63) wtot[w] = inc;
    __syncthreads();
    u32 woff = 0;
    for (int i = 0; i < w; ++i) woff += wtot[i];
    if (n < Nn) rowptr[n] = woff + inc - c;
    if (tid == 255) bsum[blockIdx.x] = woff + inc;
}
__global__ __launch_bounds__(256) void gno_scan2(u32* __restrict__ bsum, const int nb)
{
    __shared__ u32 wtot[4];
    const int tid = threadIdx.x, lane = tid & 63, w = tid >> 6;
    const u32 c = (tid < nb) ? bsum[tid] : 0u;
    u32 inc = c;
    #pragma unroll
    for (int off = 1; off < 64; off <<= 1) {
        u32 x = __shfl_up(inc, off, 64);
        if (lane >= off) inc += x;
    }
    if (lane == 63) wtot[w] = inc;
    __syncthreads();
    u32 woff = 0;
    for (int i = 0; i < w; ++i) woff += wtot[i];
    if (tid < nb) bsum[tid] = woff + inc - c;
}
__global__ __launch_bounds__(256) void gno_scan3(u32* __restrict__ rowptr,
                                                 const u32* __restrict__ bsum,
                                                 u32* __restrict__ fill)
{
    const int n = blockIdx.x * 256 + threadIdx.x;
    if (n < Nn) {
        const u32 v = rowptr[n] + bsum[blockIdx.x];
        rowptr[n] = v;
        fill[n] = v;
    }
    if (n == 0) rowptr[Nn] = En;
}
// slot-assign: plain scattered store (nt-store refuted in round 13: 68->74 MB WRITE)
__global__ void gno_slot(const int* __restrict__ neigh, u32* __restrict__ fill,
                         u32* __restrict__ pairs) {
    const int e = blockIdx.x * 256 + threadIdx.x;
    if (e < En) {
        const int dn = neigh[e];
        const int sn = neigh[En + e];
        const u32 s = atomicAdd(&fill[dn], 1u);
        pairs[s] = (u32)sn | ((u32)dn << 16);
    }
}

// ---- edge MLP over CSR slot order: 4 waves x 64 slots per block ----
// M-split (two 32-channel halves per layer) proven spill-free at (256,4) with
// ~50 µs/dispatch, 54% stall. Round 14 experiment: (256,5) -> VGPR budget 102.
// M-split peak live ~95 regs should fit. TRIPWIRE: if WRITE_SIZE >> 15.7 MB,
// the allocator spilled -> revert to (256,4) permanently.
__global__ __launch_bounds__(256, 5) void gno_edge_mfma(
    const float* __restrict__ batch, const float* __restrict__ points,
    const u32* __restrict__ pairs, const unsigned char* __restrict__ wblob,
    const int b, u16* __restrict__ msg)
{
    __shared__ __align__(128) unsigned char feat_lds[4 * 64 * 64];  // [w][e][32 bf16]
    __shared__ __align__(16) unsigned char by_lds[4 * 64 * 16];     // [w][e][8 bf16]

    const int tid = threadIdx.x;
    const int lane = tid & 63;
    const int w = tid >> 6;
    const int s0 = (blockIdx.x * 4 + w) * 64;
    if (s0 >= En) return;                  // wave-uniform tail guard; no barriers
    const int t = lane & 15;
    const int g = lane >> 4;

    // stage feat: all 64 lanes, one slot each (wave-private region, in-wave ordering)
    {
        const u32 p = pairs[s0 + lane];
        const int sn = (int)(p & 0xffffu);
        const int dn = (int)(p >> 16);
        const float2 ps = *(const float2*)(points + 2 * (size_t)sn);
        const float2 pd = *(const float2*)(points + 2 * (size_t)dn);
        const float4* bxp = (const float4*)(batch + ((size_t)b * Nn + sn) * 8);
        const float4 bx0 = bxp[0], bx1 = bxp[1];
        const float4* byp = (const float4*)(batch + ((size_t)b * Nn + dn) * 8);
        const float4 by0 = byp[0], by1 = byp[1];
        unsigned char* fb = feat_lds + w * 4096;
        const int base = lane << 6;
        const int sw = (lane & 7) << 4;
        *(uint4*)(fb + ((base + 0)  ^ sw)) = make_uint4(pkbf(ps.x, ps.y), pkbf(pd.x, pd.y),
                                                        pkbf(bx0.x, bx0.y), pkbf(bx0.z, bx0.w));
        *(uint4*)(fb + ((base + 16) ^ sw)) = make_uint4(pkbf(bx1.x, bx1.y), pkbf(bx1.z, bx1.w),
                                                        pkbf(by0.x, by0.y), pkbf(by0.z, by0.w));
        *(uint4*)(fb + ((base + 32) ^ sw)) = make_uint4(pkbf(by1.x, by1.y), pkbf(by1.z, by1.w), 0u, 0u);
        *(uint4*)(fb + ((base + 48) ^ sw)) = make_uint4(0u, 0u, 0u, 0u);
        *(uint4*)(by_lds + w * 1024 + lane * 16) = make_uint4(pkbf(by0.x, by0.y), pkbf(by0.z, by0.w),
                                                              pkbf(by1.x, by1.y), pkbf(by1.z, by1.w));
    }

    u32 pk1[4][4][2];   // L1 outputs, packed bf16 (sigma: lane-held == lane-needed)

    // ----- L1 (K=32), M in two halves -----
    {
        bf16x8 bfr[4];
        #pragma unroll
        for (int nj = 0; nj < 4; ++nj) {
            const int row = nj * 16 + t;
            bfr[nj] = *(const bf16x8*)(feat_lds + w * 4096 + ((row * 64 + (g << 4)) ^ ((row & 7) << 4)));
        }
        #pragma unroll
        for (int h = 0; h < 2; ++h) {
            f32x4 acc[2][4];
            bf16x8 afr[2];
            #pragma unroll
            for (int d = 0; d < 2; ++d) {
                const int mi = 2 * h + d;
                const f32x4 bv = *(const f32x4*)(wblob + B1_OFF + (mi * 16 + g * 4) * 4);
                #pragma unroll
                for (int nj = 0; nj < 4; ++nj) acc[d][nj] = bv;
                afr[d] = *(const bf16x8*)(wblob + W1T_OFF + (mi * 16 + t) * 64 + (g << 4));
            }
            #pragma unroll
            for (int d = 0; d < 2; ++d)
                #pragma unroll
                for (int nj = 0; nj < 4; ++nj)
                    acc[d][nj] = __builtin_amdgcn_mfma_f32_16x16x32_bf16(afr[d], bfr[nj], acc[d][nj], 0, 0, 0);
            #pragma unroll
            for (int d = 0; d < 2; ++d)
                #pragma unroll
                for (int nj = 0; nj < 4; ++nj) {
                    pk1[2 * h + d][nj][0] = pkbf(fast_tanh(acc[d][nj][0]), fast_tanh(acc[d][nj][1]));
                    pk1[2 * h + d][nj][1] = pkbf(fast_tanh(acc[d][nj][2]), fast_tanh(acc[d][nj][3]));
                }
        }
    }

    // ----- L2 (K=64), M in two halves; B-frags from pk1 registers -----
    u32 pk2[4][4][2];
    #pragma unroll
    for (int h = 0; h < 2; ++h) {
        f32x4 acc[2][4];
        #pragma unroll
        for (int d = 0; d < 2; ++d) {
            const int mi = 2 * h + d;
            const f32x4 bv = *(const f32x4*)(wblob + B2_OFF + (mi * 16 + g * 4) * 4);
            #pragma unroll
            for (int nj = 0; nj < 4; ++nj) acc[d][nj] = bv;
        }
        #pragma unroll
        for (int kt = 0; kt < 2; ++kt) {
            bf16x8 afr[2];
            #pragma unroll
            for (int d = 0; d < 2; ++d)
                afr[d] = *(const bf16x8*)(wblob + W2T_OFF + ((2 * h + d) * 16 + t) * 128 + kt * 64 + (g << 4));
            #pragma unroll
            for (int nj = 0; nj < 4; ++nj) {
                const i32x4 bi = { (int)pk1[2 * kt][nj][0], (int)pk1[2 * kt][nj][1],
                                   (int)pk1[2 * kt + 1][nj][0], (int)pk1[2 * kt + 1][nj][1] };
                const bf16x8 bf = __builtin_bit_cast(bf16x8, bi);
                #pragma unroll
                for (int d = 0; d < 2; ++d)
                    acc[d][nj] = __builtin_amdgcn_mfma_f32_16x16x32_bf16(afr[d], bf, acc[d][nj], 0, 0, 0);
            }
        }
        #pragma unroll
        for (int d = 0; d < 2; ++d)
            #pragma unroll
            for (int nj = 0; nj < 4; ++nj) {
                pk2[2 * h + d][nj][0] = pkbf(fast_tanh(acc[d][nj][0]), fast_tanh(acc[d][nj][1]));
                pk2[2 * h + d][nj][1] = pkbf(fast_tanh(acc[d][nj][2]), fast_tanh(acc[d][nj][3]));
            }
    }

    // ----- L3 (K=64) + fused epilogue, M in two halves -----
    // half h covers mats cols c = 16*(2h+d)+4g+r -> output channels 4h..4h+3.
    const int jhalf = g & 1;
    #pragma unroll
    for (int h = 0; h < 2; ++h) {
        f32x4 acc[2][4];
        #pragma unroll
        for (int d = 0; d < 2; ++d) {
            const int mi = 2 * h + d;
            const f32x4 bv = *(const f32x4*)(wblob + B3_OFF + (mi * 16 + g * 4) * 4);
            #pragma unroll
            for (int nj = 0; nj < 4; ++nj) acc[d][nj] = bv;
        }
        #pragma unroll
        for (int kt = 0; kt < 2; ++kt) {
            bf16x8 afr[2];
            #pragma unroll
            for (int d = 0; d < 2; ++d)
                afr[d] = *(const bf16x8*)(wblob + W3T_OFF + ((2 * h + d) * 16 + t) * 128 + kt * 64 + (g << 4));
            #pragma unroll
            for (int nj = 0; nj < 4; ++nj) {
                const i32x4 bi = { (int)pk2[2 * kt][nj][0], (int)pk2[2 * kt][nj][1],
                                   (int)pk2[2 * kt + 1][nj][0], (int)pk2[2 * kt + 1][nj][1] };
                const bf16x8 bf = __builtin_bit_cast(bf16x8, bi);
                #pragma unroll
                for (int d = 0; d < 2; ++d)
                    acc[d][nj] = __builtin_amdgcn_mfma_f32_16x16x32_bf16(afr[d], bf, acc[d][nj], 0, 0, 0);
            }
        }
        // epilogue for channels 4h..4h+3: i = 2*(2h+d)+(g>>1), j = jhalf*4+r
        #pragma unroll
        for (int nj = 0; nj < 4; ++nj) {
            const int el = nj * 16 + t;
            const uint2 byw = *(const uint2*)(by_lds + w * 1024 + el * 16 + jhalf * 8);
            const float f0 = bflo(byw.x), f1 = bfhi(byw.x), f2 = bflo(byw.y), f3 = bfhi(byw.y);
            u32 pks[2];
            #pragma unroll
            for (int d = 0; d < 2; ++d) {
                const f32x4 a = acc[d][nj];
                float p = fmaf(a[0], f0, fmaf(a[1], f1, fmaf(a[2], f2, a[3] * f3)));
                const float m  = p + __shfl_xor(p, 16, 64);   // full dot
                const float mo = __shfl_xor(m, 32, 64);       // partner channel
                pks[d] = pkbf(m, mo);                          // (2mi, 2mi+1) on g==0
            }
            if (g == 0)
                *(uint2*)(msg + (size_t)(s0 + el) * 8 + h * 4) = make_uint2(pks[0], pks[1]);
        }
    }
}

// ---- fused CSR gather + finalize: 8 lanes per node ----
__global__ __launch_bounds__(256) void gno_gather_out(
    const float* __restrict__ batch, const float* __restrict__ Wlin,
    const u16* __restrict__ msg, const u32* __restrict__ rowptr,
    const u32* __restrict__ cnt, float* __restrict__ out, const int b)
{
    const int tid = threadIdx.x;
    const int n = blockIdx.x * 32 + (tid >> 3);
    const int c = tid & 7;
    if (n >= Nn) return;
    const u32 dg = cnt[n];
    const u32 j0 = rowptr[n];
    float acc = 0.0f;
    for (u32 j = j0; j < j0 + dg; ++j) acc += bfu(msg[(size_t)j * 8 + c]);
    float v = acc * __builtin_amdgcn_rcpf((float)dg + 1.0f);
    const float* br = batch + ((size_t)b * Nn + n) * 8;
    #pragma unroll
    for (int j = 0; j < 8; ++j) v = fmaf(br[j], Wlin[j * FOUT + c], v);
    out[((size_t)b * Nn + n) * 8 + c] = v;   // coalesced
}

extern "C" void kernel_launch(void* const* d_in, const int* in_sizes, int n_in,
                              void* d_out, int out_size, void* d_ws, size_t ws_size,
                              hipStream_t stream) {
    const float* batch  = (const float*)d_in[0];
    const float* points = (const float*)d_in[1];
    const int*   neigh  = (const int*)d_in[2];
    const float* W1     = (const float*)d_in[3];
    const float* b1     = (const float*)d_in[4];
    const float* W2     = (const float*)d_in[5];
    const float* b2     = (const float*)d_in[6];
    const float* W3     = (const float*)d_in[7];
    const float* b3     = (const float*)d_in[8];
    const float* Wlin   = (const float*)d_in[9];
    float* out = (float*)d_out;

    unsigned char* ws = (unsigned char*)d_ws;
    u32* cnt    = (u32*)(ws + CNT_OFF);
    u32* rowptr = (u32*)(ws + ROWPTR_OFF);
    u32* fill   = (u32*)(ws + FILL_OFF);
    u32* bsum   = (u32*)(ws + BSUM_OFF);
    u32* pairs  = (u32*)(ws + PAIRS_OFF);
    u16* msg    = (u16*)(ws + MSG_OFF);
    if (ws_size < WS_NEEDED) return;

    const dim3 b256(256);
    const dim3 gE((En + 255) / 256);
    const dim3 gEdge((En / 64 + 3) / 4);     // 3907 blocks, 4 waves x 64 slots
    const dim3 gN((Nn + 255) / 256);         // 196 (<= 256 for scan2)
    const dim3 gGather((Nn + 31) / 32);

    hipMemsetAsync(cnt, 0, Nn * sizeof(u32), stream);
    gno_init_weights<<<dim3(41), b256, 0, stream>>>(W1, b1, W2, b2, W3, b3, ws);
    gno_hist<<<gE, b256, 0, stream>>>(neigh, cnt);
    gno_scan1<<<gN, b256, 0, stream>>>(cnt, rowptr, bsum);
    gno_scan2<<<dim3(1), b256, 0, stream>>>(bsum, (int)gN.x);
    gno_scan3<<<gN, b256, 0, stream>>>(rowptr, bsum, fill);
    gno_slot<<<gE, b256, 0, stream>>>(neigh, fill, pairs);
    for (int b = 0; b < Bn; ++b) {
        gno_edge_mfma<<<gEdge, b256, 0, stream>>>(batch, points, pairs, ws, b, msg);
        gno_gather_out<<<gGather, b256, 0, stream>>>(batch, Wlin, msg, rowptr, cnt, out, b);
    }
}

// Round 15
// 356.212 us; speedup vs baseline: 1.2080x; 1.2080x over previous
//
#include <hip/hip_runtime.h>

#define Bn 4
#define Nn 50000
#define En 1000000
#define FOUT 8

typedef unsigned int u32;
typedef unsigned short u16;
typedef __attribute__((ext_vector_type(8))) short bf16x8;
typedef __attribute__((ext_vector_type(4))) float f32x4;
typedef __attribute__((ext_vector_type(4))) int i32x4;

// ---- ws layout (bytes) ----
#define BLOB_BYTES 24576
#define W1T_OFF 0       // [64 q][32 k] bf16 (k padded 20->32)
#define W2T_OFF 4096    // [64 q][64 k] bf16
#define W3T_OFF 12288   // [64 c][64 k] bf16
#define B1_OFF 20480    // f32[64] sigma-permuted
#define B2_OFF 20736
#define B3_OFF 20992
#define BSUM_OFF 21248  // u32[256] in blob slack

#define CNT_OFF    24576
#define ROWPTR_OFF 224576
#define FILL_OFF   424704
#define PAIRS_OFF  624768                        // u32[En]: src | dst<<16  (Nn < 2^16)
#define MSG_OFF    4624768                       // bf16[En*8]
#define WS_NEEDED (MSG_OFF + (size_t)En * FOUT * 2)   // 20,624,768 B (round-6 proven)

__device__ __forceinline__ float fast_tanh(float x) {
    float e = __builtin_amdgcn_exp2f(x * 2.8853900817779268f);
    return 1.0f - 2.0f * __builtin_amdgcn_rcpf(e + 1.0f);
}
__device__ __forceinline__ u32 pkbf(float lo, float hi) {
    u32 r;
    asm("v_cvt_pk_bf16_f32 %0, %1, %2" : "=v"(r) : "v"(lo), "v"(hi));
    return r;
}
__device__ __forceinline__ float bflo(u32 u) { return __builtin_bit_cast(float, u << 16); }
__device__ __forceinline__ float bfhi(u32 u) { return __builtin_bit_cast(float, u & 0xffff0000u); }
__device__ __forceinline__ u16 f2bf(float x) {
    u32 u = __builtin_bit_cast(u32, x);
    return (u16)((u + 0x7fff + ((u >> 16) & 1)) >> 16);
}
// sigma-permutation of MLP hidden channels (HW-verified rounds 4-14)
__device__ __forceinline__ int PERM_Q(int q) {
    int mi = q >> 4, g = (q >> 2) & 3, r = q & 3;
    return ((mi >> 1) << 5) | (g << 3) | ((mi & 1) << 2) | r;
}

__global__ void gno_init_weights(const float* __restrict__ W1, const float* __restrict__ b1,
                                 const float* __restrict__ W2, const float* __restrict__ b2,
                                 const float* __restrict__ W3, const float* __restrict__ b3,
                                 unsigned char* __restrict__ blob)
{
    int idx = blockIdx.x * 256 + threadIdx.x;
    if (idx < 2048) {
        int q = idx >> 5, k = idx & 31;
        float v = (k < 20) ? W1[k * 64 + PERM_Q(q)] : 0.0f;
        *(u16*)(blob + W1T_OFF + q * 64 + 2 * k) = f2bf(v);
    } else if (idx < 6144) {
        int j = idx - 2048, q = j >> 6, k = j & 63;
        *(u16*)(blob + W2T_OFF + q * 128 + 2 * k) = f2bf(W2[k * 64 + PERM_Q(q)]);
    } else if (idx < 10240) {
        int j = idx - 6144, c = j >> 6, k = j & 63;
        *(u16*)(blob + W3T_OFF + c * 128 + 2 * k) = f2bf(W3[k * 64 + c]);
    } else if (idx < 10304) { int q = idx - 10240; *(float*)(blob + B1_OFF + q * 4) = b1[PERM_Q(q)]; }
    else if (idx < 10368)   { int q = idx - 10304; *(float*)(blob + B2_OFF + q * 4) = b2[PERM_Q(q)]; }
    else if (idx < 10432)   { int c = idx - 10368; *(float*)(blob + B3_OFF + c * 4) = b3[c]; }
}

// ---- CSR build ----
__global__ void gno_hist(const int* __restrict__ neigh, u32* __restrict__ cnt) {
    const int e = blockIdx.x * 256 + threadIdx.x;
    if (e < En) atomicAdd(&cnt[neigh[e]], 1u);
}
__global__ __launch_bounds__(256) void gno_scan1(const u32* __restrict__ cnt,
                                                 u32* __restrict__ rowptr,
                                                 u32* __restrict__ bsum)
{
    __shared__ u32 wtot[4];
    const int tid = threadIdx.x, lane = tid & 63, w = tid >> 6;
    const int n = blockIdx.x * 256 + tid;
    const u32 c = (n < Nn) ? cnt[n] : 0u;
    u32 inc = c;
    #pragma unroll
    for (int off = 1; off < 64; off <<= 1) {
        u32 x = __shfl_up(inc, off, 64);
        if (lane >= off) inc += x;
    }
    if (lane == 63) wtot[w] = inc;
    __syncthreads();
    u32 woff = 0;
    for (int i = 0; i < w; ++i) woff += wtot[i];
    if (n < Nn) rowptr[n] = woff + inc - c;
    if (tid == 255) bsum[blockIdx.x] = woff + inc;
}
__global__ __launch_bounds__(256) void gno_scan2(u32* __restrict__ bsum, const int nb)
{
    __shared__ u32 wtot[4];
    const int tid = threadIdx.x, lane = tid & 63, w = tid >> 6;
    const u32 c = (tid < nb) ? bsum[tid] : 0u;
    u32 inc = c;
    #pragma unroll
    for (int off = 1; off < 64; off <<= 1) {
        u32 x = __shfl_up(inc, off, 64);
        if (lane >= off) inc += x;
    }
    if (lane == 63) wtot[w] = inc;
    __syncthreads();
    u32 woff = 0;
    for (int i = 0; i < w; ++i) woff += wtot[i];
    if (tid < nb) bsum[tid] = woff + inc - c;
}
__global__ __launch_bounds__(256) void gno_scan3(u32* __restrict__ rowptr,
                                                 const u32* __restrict__ bsum,
                                                 u32* __restrict__ fill)
{
    const int n = blockIdx.x * 256 + threadIdx.x;
    if (n < Nn) {
        const u32 v = rowptr[n] + bsum[blockIdx.x];
        rowptr[n] = v;
        fill[n] = v;
    }
    if (n == 0) rowptr[Nn] = En;
}
// slot-assign: plain scattered store (nt refuted r13; scatter churn is the sort's price)
__global__ void gno_slot(const int* __restrict__ neigh, u32* __restrict__ fill,
                         u32* __restrict__ pairs) {
    const int e = blockIdx.x * 256 + threadIdx.x;
    if (e < En) {
        const int dn = neigh[e];
        const int sn = neigh[En + e];
        const u32 s = atomicAdd(&fill[dn], 1u);
        pairs[s] = (u32)sn | ((u32)dn << 16);
    }
}

// ---- edge MLP over CSR slot order: 4 waves x 64 slots per block ----
// PERMANENT: (256,4). Register-wall ledger: (256,5) spilled twice (r8: 280MB,
// r14: 82MB scratch WRITE), (256,8) spilled (r10: 412MB), T14 pipeline spilled
// (r12). M-split at (256,4) is the proven spill-free floor (~50 µs/dispatch).
__global__ __launch_bounds__(256, 4) void gno_edge_mfma(
    const float* __restrict__ batch, const float* __restrict__ points,
    const u32* __restrict__ pairs, const unsigned char* __restrict__ wblob,
    const int b, u16* __restrict__ msg)
{
    __shared__ __align__(128) unsigned char feat_lds[4 * 64 * 64];  // [w][e][32 bf16]
    __shared__ __align__(16) unsigned char by_lds[4 * 64 * 16];     // [w][e][8 bf16]

    const int tid = threadIdx.x;
    const int lane = tid & 63;
    const int w = tid >> 6;
    const int s0 = (blockIdx.x * 4 + w) * 64;
    if (s0 >= En) return;                  // wave-uniform tail guard; no barriers
    const int t = lane & 15;
    const int g = lane >> 4;

    // stage feat: all 64 lanes, one slot each (wave-private region, in-wave ordering)
    {
        const u32 p = pairs[s0 + lane];
        const int sn = (int)(p & 0xffffu);
        const int dn = (int)(p >> 16);
        const float2 ps = *(const float2*)(points + 2 * (size_t)sn);
        const float2 pd = *(const float2*)(points + 2 * (size_t)dn);
        const float4* bxp = (const float4*)(batch + ((size_t)b * Nn + sn) * 8);
        const float4 bx0 = bxp[0], bx1 = bxp[1];
        const float4* byp = (const float4*)(batch + ((size_t)b * Nn + dn) * 8);
        const float4 by0 = byp[0], by1 = byp[1];
        unsigned char* fb = feat_lds + w * 4096;
        const int base = lane << 6;
        const int sw = (lane & 7) << 4;
        *(uint4*)(fb + ((base + 0)  ^ sw)) = make_uint4(pkbf(ps.x, ps.y), pkbf(pd.x, pd.y),
                                                        pkbf(bx0.x, bx0.y), pkbf(bx0.z, bx0.w));
        *(uint4*)(fb + ((base + 16) ^ sw)) = make_uint4(pkbf(bx1.x, bx1.y), pkbf(bx1.z, bx1.w),
                                                        pkbf(by0.x, by0.y), pkbf(by0.z, by0.w));
        *(uint4*)(fb + ((base + 32) ^ sw)) = make_uint4(pkbf(by1.x, by1.y), pkbf(by1.z, by1.w), 0u, 0u);
        *(uint4*)(fb + ((base + 48) ^ sw)) = make_uint4(0u, 0u, 0u, 0u);
        *(uint4*)(by_lds + w * 1024 + lane * 16) = make_uint4(pkbf(by0.x, by0.y), pkbf(by0.z, by0.w),
                                                              pkbf(by1.x, by1.y), pkbf(by1.z, by1.w));
    }

    u32 pk1[4][4][2];   // L1 outputs, packed bf16 (sigma: lane-held == lane-needed)

    // ----- L1 (K=32), M in two halves -----
    {
        bf16x8 bfr[4];
        #pragma unroll
        for (int nj = 0; nj < 4; ++nj) {
            const int row = nj * 16 + t;
            bfr[nj] = *(const bf16x8*)(feat_lds + w * 4096 + ((row * 64 + (g << 4)) ^ ((row & 7) << 4)));
        }
        #pragma unroll
        for (int h = 0; h < 2; ++h) {
            f32x4 acc[2][4];
            bf16x8 afr[2];
            #pragma unroll
            for (int d = 0; d < 2; ++d) {
                const int mi = 2 * h + d;
                const f32x4 bv = *(const f32x4*)(wblob + B1_OFF + (mi * 16 + g * 4) * 4);
                #pragma unroll
                for (int nj = 0; nj < 4; ++nj) acc[d][nj] = bv;
                afr[d] = *(const bf16x8*)(wblob + W1T_OFF + (mi * 16 + t) * 64 + (g << 4));
            }
            #pragma unroll
            for (int d = 0; d < 2; ++d)
                #pragma unroll
                for (int nj = 0; nj < 4; ++nj)
                    acc[d][nj] = __builtin_amdgcn_mfma_f32_16x16x32_bf16(afr[d], bfr[nj], acc[d][nj], 0, 0, 0);
            #pragma unroll
            for (int d = 0; d < 2; ++d)
                #pragma unroll
                for (int nj = 0; nj < 4; ++nj) {
                    pk1[2 * h + d][nj][0] = pkbf(fast_tanh(acc[d][nj][0]), fast_tanh(acc[d][nj][1]));
                    pk1[2 * h + d][nj][1] = pkbf(fast_tanh(acc[d][nj][2]), fast_tanh(acc[d][nj][3]));
                }
        }
    }

    // ----- L2 (K=64), M in two halves; B-frags from pk1 registers -----
    u32 pk2[4][4][2];
    #pragma unroll
    for (int h = 0; h < 2; ++h) {
        f32x4 acc[2][4];
        #pragma unroll
        for (int d = 0; d < 2; ++d) {
            const int mi = 2 * h + d;
            const f32x4 bv = *(const f32x4*)(wblob + B2_OFF + (mi * 16 + g * 4) * 4);
            #pragma unroll
            for (int nj = 0; nj < 4; ++nj) acc[d][nj] = bv;
        }
        #pragma unroll
        for (int kt = 0; kt < 2; ++kt) {
            bf16x8 afr[2];
            #pragma unroll
            for (int d = 0; d < 2; ++d)
                afr[d] = *(const bf16x8*)(wblob + W2T_OFF + ((2 * h + d) * 16 + t) * 128 + kt * 64 + (g << 4));
            #pragma unroll
            for (int nj = 0; nj < 4; ++nj) {
                const i32x4 bi = { (int)pk1[2 * kt][nj][0], (int)pk1[2 * kt][nj][1],
                                   (int)pk1[2 * kt + 1][nj][0], (int)pk1[2 * kt + 1][nj][1] };
                const bf16x8 bf = __builtin_bit_cast(bf16x8, bi);
                #pragma unroll
                for (int d = 0; d < 2; ++d)
                    acc[d][nj] = __builtin_amdgcn_mfma_f32_16x16x32_bf16(afr[d], bf, acc[d][nj], 0, 0, 0);
            }
        }
        #pragma unroll
        for (int d = 0; d < 2; ++d)
            #pragma unroll
            for (int nj = 0; nj < 4; ++nj) {
                pk2[2 * h + d][nj][0] = pkbf(fast_tanh(acc[d][nj][0]), fast_tanh(acc[d][nj][1]));
                pk2[2 * h + d][nj][1] = pkbf(fast_tanh(acc[d][nj][2]), fast_tanh(acc[d][nj][3]));
            }
    }

    // ----- L3 (K=64) + fused epilogue, M in two halves -----
    const int jhalf = g & 1;
    #pragma unroll
    for (int h = 0; h < 2; ++h) {
        f32x4 acc[2][4];
        #pragma unroll
        for (int d = 0; d < 2; ++d) {
            const int mi = 2 * h + d;
            const f32x4 bv = *(const f32x4*)(wblob + B3_OFF + (mi * 16 + g * 4) * 4);
            #pragma unroll
            for (int nj = 0; nj < 4; ++nj) acc[d][nj] = bv;
        }
        #pragma unroll
        for (int kt = 0; kt < 2; ++kt) {
            bf16x8 afr[2];
            #pragma unroll
            for (int d = 0; d < 2; ++d)
                afr[d] = *(const bf16x8*)(wblob + W3T_OFF + ((2 * h + d) * 16 + t) * 128 + kt * 64 + (g << 4));
            #pragma unroll
            for (int nj = 0; nj < 4; ++nj) {
                const i32x4 bi = { (int)pk2[2 * kt][nj][0], (int)pk2[2 * kt][nj][1],
                                   (int)pk2[2 * kt + 1][nj][0], (int)pk2[2 * kt + 1][nj][1] };
                const bf16x8 bf = __builtin_bit_cast(bf16x8, bi);
                #pragma unroll
                for (int d = 0; d < 2; ++d)
                    acc[d][nj] = __builtin_amdgcn_mfma_f32_16x16x32_bf16(afr[d], bf, acc[d][nj], 0, 0, 0);
            }
        }
        // epilogue for channels 4h..4h+3: i = 2*(2h+d)+(g>>1), j = jhalf*4+r
        #pragma unroll
        for (int nj = 0; nj < 4; ++nj) {
            const int el = nj * 16 + t;
            const uint2 byw = *(const uint2*)(by_lds + w * 1024 + el * 16 + jhalf * 8);
            const float f0 = bflo(byw.x), f1 = bfhi(byw.x), f2 = bflo(byw.y), f3 = bfhi(byw.y);
            u32 pks[2];
            #pragma unroll
            for (int d = 0; d < 2; ++d) {
                const f32x4 a = acc[d][nj];
                float p = fmaf(a[0], f0, fmaf(a[1], f1, fmaf(a[2], f2, a[3] * f3)));
                const float m  = p + __shfl_xor(p, 16, 64);   // full dot
                const float mo = __shfl_xor(m, 32, 64);       // partner channel
                pks[d] = pkbf(m, mo);                          // (2mi, 2mi+1) on g==0
            }
            if (g == 0)
                *(uint2*)(msg + (size_t)(s0 + el) * 8 + h * 4) = make_uint2(pks[0], pks[1]);
        }
    }
}

// ---- fused CSR gather + finalize: 8 lanes per node, COALESCED slot reads ----
// Lane k of each 8-lane group reads whole slots j0+k, j0+k+8, ... as uint4 (16B);
// consecutive lanes -> consecutive slots -> 128B coalesced bursts. Each lane
// accumulates all 8 channels; 3-step shfl_xor tree sums the group; lane k then
// finalizes channel k. (Round-13 version read 2B/lane at stride 16B: ~1/8 eff.)
__global__ __launch_bounds__(256) void gno_gather_out(
    const float* __restrict__ batch, const float* __restrict__ Wlin,
    const u16* __restrict__ msg, const u32* __restrict__ rowptr,
    const u32* __restrict__ cnt, float* __restrict__ out, const int b)
{
    const int tid = threadIdx.x;
    const int n = blockIdx.x * 32 + (tid >> 3);
    const int k = tid & 7;
    if (n >= Nn) return;
    const u32 dg = cnt[n];
    const u32 j0 = rowptr[n];
    float acc[8] = {0, 0, 0, 0, 0, 0, 0, 0};
    for (u32 j = j0 + k; j < j0 + dg; j += 8) {
        const uint4 m = *(const uint4*)(msg + (size_t)j * 8);
        acc[0] += bflo(m.x); acc[1] += bfhi(m.x);
        acc[2] += bflo(m.y); acc[3] += bfhi(m.y);
        acc[4] += bflo(m.z); acc[5] += bfhi(m.z);
        acc[6] += bflo(m.w); acc[7] += bfhi(m.w);
    }
    #pragma unroll
    for (int s = 1; s < 8; s <<= 1) {
        #pragma unroll
        for (int c = 0; c < 8; ++c) acc[c] += __shfl_xor(acc[c], s, 64);
    }
    float v = acc[k] * __builtin_amdgcn_rcpf((float)dg + 1.0f);
    const float* br = batch + ((size_t)b * Nn + n) * 8;
    #pragma unroll
    for (int j = 0; j < 8; ++j) v = fmaf(br[j], Wlin[j * FOUT + k], v);
    out[((size_t)b * Nn + n) * 8 + k] = v;   // fully coalesced
}

extern "C" void kernel_launch(void* const* d_in, const int* in_sizes, int n_in,
                              void* d_out, int out_size, void* d_ws, size_t ws_size,
                              hipStream_t stream) {
    const float* batch  = (const float*)d_in[0];
    const float* points = (const float*)d_in[1];
    const int*   neigh  = (const int*)d_in[2];
    const float* W1     = (const float*)d_in[3];
    const float* b1     = (const float*)d_in[4];
    const float* W2     = (const float*)d_in[5];
    const float* b2     = (const float*)d_in[6];
    const float* W3     = (const float*)d_in[7];
    const float* b3     = (const float*)d_in[8];
    const float* Wlin   = (const float*)d_in[9];
    float* out = (float*)d_out;

    unsigned char* ws = (unsigned char*)d_ws;
    u32* cnt    = (u32*)(ws + CNT_OFF);
    u32* rowptr = (u32*)(ws + ROWPTR_OFF);
    u32* fill   = (u32*)(ws + FILL_OFF);
    u32* bsum   = (u32*)(ws + BSUM_OFF);
    u32* pairs  = (u32*)(ws + PAIRS_OFF);
    u16* msg    = (u16*)(ws + MSG_OFF);
    if (ws_size < WS_NEEDED) return;

    const dim3 b256(256);
    const dim3 gE((En + 255) / 256);
    const dim3 gEdge((En / 64 + 3) / 4);     // 3907 blocks, 4 waves x 64 slots
    const dim3 gN((Nn + 255) / 256);         // 196 (<= 256 for scan2)
    const dim3 gGather((Nn + 31) / 32);

    hipMemsetAsync(cnt, 0, Nn * sizeof(u32), stream);
    gno_init_weights<<<dim3(41), b256, 0, stream>>>(W1, b1, W2, b2, W3, b3, ws);
    gno_hist<<<gE, b256, 0, stream>>>(neigh, cnt);
    gno_scan1<<<gN, b256, 0, stream>>>(cnt, rowptr, bsum);
    gno_scan2<<<dim3(1), b256, 0, stream>>>(bsum, (int)gN.x);
    gno_scan3<<<gN, b256, 0, stream>>>(rowptr, bsum, fill);
    gno_slot<<<gE, b256, 0, stream>>>(neigh, fill, pairs);
    for (int b = 0; b < Bn; ++b) {
        gno_edge_mfma<<<gEdge, b256, 0, stream>>>(batch, points, pairs, ws, b, msg);
        gno_gather_out<<<gGather, b256, 0, stream>>>(batch, Wlin, msg, rowptr, cnt, out, b);
    }
}

// Round 16
// 353.997 us; speedup vs baseline: 1.2156x; 1.0063x over previous
//
#include <hip/hip_runtime.h>

#define Bn 4
#define Nn 50000
#define En 1000000
#define FOUT 8

typedef unsigned int u32;
typedef unsigned short u16;
typedef __attribute__((ext_vector_type(8))) short bf16x8;
typedef __attribute__((ext_vector_type(4))) float f32x4;
typedef __attribute__((ext_vector_type(4))) int i32x4;

// ---- ws layout (bytes) ----
#define BLOB_BYTES 24576
#define W1T_OFF 0       // [64 q][32 k] bf16 (k padded 20->32)
#define W2T_OFF 4096    // [64 q][64 k] bf16
#define W3T_OFF 12288   // [64 c][64 k] bf16
#define B1_OFF 20480    // f32[64] sigma-permuted
#define B2_OFF 20736
#define B3_OFF 20992
#define BSUM_OFF 21248  // u32[256] in blob slack

#define CNT_OFF    24576
#define ROWPTR_OFF 224576
#define FILL_OFF   424704
#define PAIRS_OFF  624768                        // u32[En]: src | dst<<16  (Nn < 2^16)
#define MSG_OFF    4624768                       // bf16[En*8]
#define WS_NEEDED (MSG_OFF + (size_t)En * FOUT * 2)   // 20,624,768 B (proven)
// bf16-precvt extension (round 16): packed points + bf16 batch
#define PBF_OFF    20624768                      // u32[Nn]  (ps pair packed)
#define BBF_OFF    20824768                      // u16[Bn*Nn*8]
#define WS_CVT     (BBF_OFF + (size_t)Bn * Nn * FOUT * 2)   // 24,024,768 B

__device__ __forceinline__ float fast_tanh(float x) {
    float e = __builtin_amdgcn_exp2f(x * 2.8853900817779268f);
    return 1.0f - 2.0f * __builtin_amdgcn_rcpf(e + 1.0f);
}
__device__ __forceinline__ u32 pkbf(float lo, float hi) {
    u32 r;
    asm("v_cvt_pk_bf16_f32 %0, %1, %2" : "=v"(r) : "v"(lo), "v"(hi));
    return r;
}
__device__ __forceinline__ float bflo(u32 u) { return __builtin_bit_cast(float, u << 16); }
__device__ __forceinline__ float bfhi(u32 u) { return __builtin_bit_cast(float, u & 0xffff0000u); }
__device__ __forceinline__ u16 f2bf(float x) {
    u32 u = __builtin_bit_cast(u32, x);
    return (u16)((u + 0x7fff + ((u >> 16) & 1)) >> 16);
}
// sigma-permutation of MLP hidden channels (HW-verified rounds 4-15)
__device__ __forceinline__ int PERM_Q(int q) {
    int mi = q >> 4, g = (q >> 2) & 3, r = q & 3;
    return ((mi >> 1) << 5) | (g << 3) | ((mi & 1) << 2) | r;
}

__global__ void gno_init_weights(const float* __restrict__ W1, const float* __restrict__ b1,
                                 const float* __restrict__ W2, const float* __restrict__ b2,
                                 const float* __restrict__ W3, const float* __restrict__ b3,
                                 unsigned char* __restrict__ blob)
{
    int idx = blockIdx.x * 256 + threadIdx.x;
    if (idx < 2048) {
        int q = idx >> 5, k = idx & 31;
        float v = (k < 20) ? W1[k * 64 + PERM_Q(q)] : 0.0f;
        *(u16*)(blob + W1T_OFF + q * 64 + 2 * k) = f2bf(v);
    } else if (idx < 6144) {
        int j = idx - 2048, q = j >> 6, k = j & 63;
        *(u16*)(blob + W2T_OFF + q * 128 + 2 * k) = f2bf(W2[k * 64 + PERM_Q(q)]);
    } else if (idx < 10240) {
        int j = idx - 6144, c = j >> 6, k = j & 63;
        *(u16*)(blob + W3T_OFF + c * 128 + 2 * k) = f2bf(W3[k * 64 + c]);
    } else if (idx < 10304) { int q = idx - 10240; *(float*)(blob + B1_OFF + q * 4) = b1[PERM_Q(q)]; }
    else if (idx < 10368)   { int q = idx - 10304; *(float*)(blob + B2_OFF + q * 4) = b2[PERM_Q(q)]; }
    else if (idx < 10432)   { int c = idx - 10368; *(float*)(blob + B3_OFF + c * 4) = b3[c]; }
}

// ---- bf16 pre-conversion: batch -> bbf (u16x8/node), points -> pbf (packed pair) ----
__global__ void gno_cvt(const float* __restrict__ batch, const float* __restrict__ points,
                        u32* __restrict__ pbf, u16* __restrict__ bbf)
{
    const int t = blockIdx.x * 256 + threadIdx.x;
    if (t < Bn * Nn) {
        const float4* bp = (const float4*)(batch + (size_t)t * 8);
        const float4 a = bp[0], c = bp[1];
        *(uint4*)(bbf + (size_t)t * 8) =
            make_uint4(pkbf(a.x, a.y), pkbf(a.z, a.w), pkbf(c.x, c.y), pkbf(c.z, c.w));
    }
    if (t < Nn) {
        const float2 pp = *(const float2*)(points + 2 * (size_t)t);
        pbf[t] = pkbf(pp.x, pp.y);
    }
}

// ---- CSR build ----
__global__ void gno_hist(const int* __restrict__ neigh, u32* __restrict__ cnt) {
    const int e = blockIdx.x * 256 + threadIdx.x;
    if (e < En) atomicAdd(&cnt[neigh[e]], 1u);
}
__global__ __launch_bounds__(256) void gno_scan1(const u32* __restrict__ cnt,
                                                 u32* __restrict__ rowptr,
                                                 u32* __restrict__ bsum)
{
    __shared__ u32 wtot[4];
    const int tid = threadIdx.x, lane = tid & 63, w = tid >> 6;
    const int n = blockIdx.x * 256 + tid;
    const u32 c = (n < Nn) ? cnt[n] : 0u;
    u32 inc = c;
    #pragma unroll
    for (int off = 1; off < 64; off <<= 1) {
        u32 x = __shfl_up(inc, off, 64);
        if (lane >= off) inc += x;
    }
    if (lane == 63) wtot[w] = inc;
    __syncthreads();
    u32 woff = 0;
    for (int i = 0; i < w; ++i) woff += wtot[i];
    if (n < Nn) rowptr[n] = woff + inc - c;
    if (tid == 255) bsum[blockIdx.x] = woff + inc;
}
__global__ __launch_bounds__(256) void gno_scan2(u32* __restrict__ bsum, const int nb)
{
    __shared__ u32 wtot[4];
    const int tid = threadIdx.x, lane = tid & 63, w = tid >> 6;
    const u32 c = (tid < nb) ? bsum[tid] : 0u;
    u32 inc = c;
    #pragma unroll
    for (int off = 1; off < 64; off <<= 1) {
        u32 x = __shfl_up(inc, off, 64);
        if (lane >= off) inc += x;
    }
    if (lane == 63) wtot[w] = inc;
    __syncthreads();
    u32 woff = 0;
    for (int i = 0; i < w; ++i) woff += wtot[i];
    if (tid < nb) bsum[tid] = woff + inc - c;
}
__global__ __launch_bounds__(256) void gno_scan3(u32* __restrict__ rowptr,
                                                 const u32* __restrict__ bsum,
                                                 u32* __restrict__ fill)
{
    const int n = blockIdx.x * 256 + threadIdx.x;
    if (n < Nn) {
        const u32 v = rowptr[n] + bsum[blockIdx.x];
        rowptr[n] = v;
        fill[n] = v;
    }
    if (n == 0) rowptr[Nn] = En;
}
// slot-assign: plain scattered store (nt refuted r13; scatter churn is the sort's price)
__global__ void gno_slot(const int* __restrict__ neigh, u32* __restrict__ fill,
                         u32* __restrict__ pairs) {
    const int e = blockIdx.x * 256 + threadIdx.x;
    if (e < En) {
        const int dn = neigh[e];
        const int sn = neigh[En + e];
        const u32 s = atomicAdd(&fill[dn], 1u);
        pairs[s] = (u32)sn | ((u32)dn << 16);
    }
}

// ---- edge MLP over CSR slot order: 4 waves x 64 slots per block ----
// PERMANENT (256,4): spill ledger r8/r10/r12/r14. CVT=1: 5 gather loads/edge
// (40 B, all bf16, zero staging pkbf); CVT=0: round-15 f32 path (7 loads, 76 B).
template<int CVT>
__global__ __launch_bounds__(256, 4) void gno_edge_mfma(
    const float* __restrict__ batch, const float* __restrict__ points,
    const u32* __restrict__ pairs, const unsigned char* __restrict__ wblob,
    const int b, u16* __restrict__ msg,
    const u32* __restrict__ pbf, const u16* __restrict__ bbf)
{
    __shared__ __align__(128) unsigned char feat_lds[4 * 64 * 64];  // [w][e][32 bf16]
    __shared__ __align__(16) unsigned char by_lds[4 * 64 * 16];     // [w][e][8 bf16]

    const int tid = threadIdx.x;
    const int lane = tid & 63;
    const int w = tid >> 6;
    const int s0 = (blockIdx.x * 4 + w) * 64;
    if (s0 >= En) return;                  // wave-uniform tail guard; no barriers
    const int t = lane & 15;
    const int g = lane >> 4;

    // stage feat: all 64 lanes, one slot each (wave-private region, in-wave ordering)
    {
        const u32 p = pairs[s0 + lane];
        const int sn = (int)(p & 0xffffu);
        const int dn = (int)(p >> 16);
        unsigned char* fb = feat_lds + w * 4096;
        const int base = lane << 6;
        const int sw = (lane & 7) << 4;
        if constexpr (CVT) {
            const u32 pspk = pbf[sn];
            const u32 pdpk = pbf[dn];
            const uint4 bx = *(const uint4*)(bbf + ((size_t)b * Nn + sn) * 8);
            const uint4 by = *(const uint4*)(bbf + ((size_t)b * Nn + dn) * 8);
            *(uint4*)(fb + ((base + 0)  ^ sw)) = make_uint4(pspk, pdpk, bx.x, bx.y);
            *(uint4*)(fb + ((base + 16) ^ sw)) = make_uint4(bx.z, bx.w, by.x, by.y);
            *(uint4*)(fb + ((base + 32) ^ sw)) = make_uint4(by.z, by.w, 0u, 0u);
            *(uint4*)(fb + ((base + 48) ^ sw)) = make_uint4(0u, 0u, 0u, 0u);
            *(uint4*)(by_lds + w * 1024 + lane * 16) = by;
        } else {
            const float2 ps = *(const float2*)(points + 2 * (size_t)sn);
            const float2 pd = *(const float2*)(points + 2 * (size_t)dn);
            const float4* bxp = (const float4*)(batch + ((size_t)b * Nn + sn) * 8);
            const float4 bx0 = bxp[0], bx1 = bxp[1];
            const float4* byp = (const float4*)(batch + ((size_t)b * Nn + dn) * 8);
            const float4 by0 = byp[0], by1 = byp[1];
            *(uint4*)(fb + ((base + 0)  ^ sw)) = make_uint4(pkbf(ps.x, ps.y), pkbf(pd.x, pd.y),
                                                            pkbf(bx0.x, bx0.y), pkbf(bx0.z, bx0.w));
            *(uint4*)(fb + ((base + 16) ^ sw)) = make_uint4(pkbf(bx1.x, bx1.y), pkbf(bx1.z, bx1.w),
                                                            pkbf(by0.x, by0.y), pkbf(by0.z, by0.w));
            *(uint4*)(fb + ((base + 32) ^ sw)) = make_uint4(pkbf(by1.x, by1.y), pkbf(by1.z, by1.w), 0u, 0u);
            *(uint4*)(fb + ((base + 48) ^ sw)) = make_uint4(0u, 0u, 0u, 0u);
            *(uint4*)(by_lds + w * 1024 + lane * 16) = make_uint4(pkbf(by0.x, by0.y), pkbf(by0.z, by0.w),
                                                                  pkbf(by1.x, by1.y), pkbf(by1.z, by1.w));
        }
    }

    u32 pk1[4][4][2];   // L1 outputs, packed bf16 (sigma: lane-held == lane-needed)

    // ----- L1 (K=32), M in two halves -----
    {
        bf16x8 bfr[4];
        #pragma unroll
        for (int nj = 0; nj < 4; ++nj) {
            const int row = nj * 16 + t;
            bfr[nj] = *(const bf16x8*)(feat_lds + w * 4096 + ((row * 64 + (g << 4)) ^ ((row & 7) << 4)));
        }
        #pragma unroll
        for (int h = 0; h < 2; ++h) {
            f32x4 acc[2][4];
            bf16x8 afr[2];
            #pragma unroll
            for (int d = 0; d < 2; ++d) {
                const int mi = 2 * h + d;
                const f32x4 bv = *(const f32x4*)(wblob + B1_OFF + (mi * 16 + g * 4) * 4);
                #pragma unroll
                for (int nj = 0; nj < 4; ++nj) acc[d][nj] = bv;
                afr[d] = *(const bf16x8*)(wblob + W1T_OFF + (mi * 16 + t) * 64 + (g << 4));
            }
            #pragma unroll
            for (int d = 0; d < 2; ++d)
                #pragma unroll
                for (int nj = 0; nj < 4; ++nj)
                    acc[d][nj] = __builtin_amdgcn_mfma_f32_16x16x32_bf16(afr[d], bfr[nj], acc[d][nj], 0, 0, 0);
            #pragma unroll
            for (int d = 0; d < 2; ++d)
                #pragma unroll
                for (int nj = 0; nj < 4; ++nj) {
                    pk1[2 * h + d][nj][0] = pkbf(fast_tanh(acc[d][nj][0]), fast_tanh(acc[d][nj][1]));
                    pk1[2 * h + d][nj][1] = pkbf(fast_tanh(acc[d][nj][2]), fast_tanh(acc[d][nj][3]));
                }
        }
    }

    // ----- L2 (K=64), M in two halves; B-frags from pk1 registers -----
    u32 pk2[4][4][2];
    #pragma unroll
    for (int h = 0; h < 2; ++h) {
        f32x4 acc[2][4];
        #pragma unroll
        for (int d = 0; d < 2; ++d) {
            const int mi = 2 * h + d;
            const f32x4 bv = *(const f32x4*)(wblob + B2_OFF + (mi * 16 + g * 4) * 4);
            #pragma unroll
            for (int nj = 0; nj < 4; ++nj) acc[d][nj] = bv;
        }
        #pragma unroll
        for (int kt = 0; kt < 2; ++kt) {
            bf16x8 afr[2];
            #pragma unroll
            for (int d = 0; d < 2; ++d)
                afr[d] = *(const bf16x8*)(wblob + W2T_OFF + ((2 * h + d) * 16 + t) * 128 + kt * 64 + (g << 4));
            #pragma unroll
            for (int nj = 0; nj < 4; ++nj) {
                const i32x4 bi = { (int)pk1[2 * kt][nj][0], (int)pk1[2 * kt][nj][1],
                                   (int)pk1[2 * kt + 1][nj][0], (int)pk1[2 * kt + 1][nj][1] };
                const bf16x8 bf = __builtin_bit_cast(bf16x8, bi);
                #pragma unroll
                for (int d = 0; d < 2; ++d)
                    acc[d][nj] = __builtin_amdgcn_mfma_f32_16x16x32_bf16(afr[d], bf, acc[d][nj], 0, 0, 0);
            }
        }
        #pragma unroll
        for (int d = 0; d < 2; ++d)
            #pragma unroll
            for (int nj = 0; nj < 4; ++nj) {
                pk2[2 * h + d][nj][0] = pkbf(fast_tanh(acc[d][nj][0]), fast_tanh(acc[d][nj][1]));
                pk2[2 * h + d][nj][1] = pkbf(fast_tanh(acc[d][nj][2]), fast_tanh(acc[d][nj][3]));
            }
    }

    // ----- L3 (K=64) + fused epilogue, M in two halves -----
    const int jhalf = g & 1;
    #pragma unroll
    for (int h = 0; h < 2; ++h) {
        f32x4 acc[2][4];
        #pragma unroll
        for (int d = 0; d < 2; ++d) {
            const int mi = 2 * h + d;
            const f32x4 bv = *(const f32x4*)(wblob + B3_OFF + (mi * 16 + g * 4) * 4);
            #pragma unroll
            for (int nj = 0; nj < 4; ++nj) acc[d][nj] = bv;
        }
        #pragma unroll
        for (int kt = 0; kt < 2; ++kt) {
            bf16x8 afr[2];
            #pragma unroll
            for (int d = 0; d < 2; ++d)
                afr[d] = *(const bf16x8*)(wblob + W3T_OFF + ((2 * h + d) * 16 + t) * 128 + kt * 64 + (g << 4));
            #pragma unroll
            for (int nj = 0; nj < 4; ++nj) {
                const i32x4 bi = { (int)pk2[2 * kt][nj][0], (int)pk2[2 * kt][nj][1],
                                   (int)pk2[2 * kt + 1][nj][0], (int)pk2[2 * kt + 1][nj][1] };
                const bf16x8 bf = __builtin_bit_cast(bf16x8, bi);
                #pragma unroll
                for (int d = 0; d < 2; ++d)
                    acc[d][nj] = __builtin_amdgcn_mfma_f32_16x16x32_bf16(afr[d], bf, acc[d][nj], 0, 0, 0);
            }
        }
        // epilogue for channels 4h..4h+3: i = 2*(2h+d)+(g>>1), j = jhalf*4+r
        #pragma unroll
        for (int nj = 0; nj < 4; ++nj) {
            const int el = nj * 16 + t;
            const uint2 byw = *(const uint2*)(by_lds + w * 1024 + el * 16 + jhalf * 8);
            const float f0 = bflo(byw.x), f1 = bfhi(byw.x), f2 = bflo(byw.y), f3 = bfhi(byw.y);
            u32 pks[2];
            #pragma unroll
            for (int d = 0; d < 2; ++d) {
                const f32x4 a = acc[d][nj];
                float p = fmaf(a[0], f0, fmaf(a[1], f1, fmaf(a[2], f2, a[3] * f3)));
                const float m  = p + __shfl_xor(p, 16, 64);   // full dot
                const float mo = __shfl_xor(m, 32, 64);       // partner channel
                pks[d] = pkbf(m, mo);                          // (2mi, 2mi+1) on g==0
            }
            if (g == 0)
                *(uint2*)(msg + (size_t)(s0 + el) * 8 + h * 4) = make_uint2(pks[0], pks[1]);
        }
    }
}

// ---- fused CSR gather + finalize: 8 lanes per node, coalesced uint4 slot reads ----
__global__ __launch_bounds__(256) void gno_gather_out(
    const float* __restrict__ batch, const float* __restrict__ Wlin,
    const u16* __restrict__ msg, const u32* __restrict__ rowptr,
    const u32* __restrict__ cnt, float* __restrict__ out, const int b)
{
    const int tid = threadIdx.x;
    const int n = blockIdx.x * 32 + (tid >> 3);
    const int k = tid & 7;
    if (n >= Nn) return;
    const u32 dg = cnt[n];
    const u32 j0 = rowptr[n];
    float acc[8] = {0, 0, 0, 0, 0, 0, 0, 0};
    for (u32 j = j0 + k; j < j0 + dg; j += 8) {
        const uint4 m = *(const uint4*)(msg + (size_t)j * 8);
        acc[0] += bflo(m.x); acc[1] += bfhi(m.x);
        acc[2] += bflo(m.y); acc[3] += bfhi(m.y);
        acc[4] += bflo(m.z); acc[5] += bfhi(m.z);
        acc[6] += bflo(m.w); acc[7] += bfhi(m.w);
    }
    #pragma unroll
    for (int s = 1; s < 8; s <<= 1) {
        #pragma unroll
        for (int c = 0; c < 8; ++c) acc[c] += __shfl_xor(acc[c], s, 64);
    }
    float v = acc[k] * __builtin_amdgcn_rcpf((float)dg + 1.0f);
    const float* br = batch + ((size_t)b * Nn + n) * 8;
    #pragma unroll
    for (int j = 0; j < 8; ++j) v = fmaf(br[j], Wlin[j * FOUT + k], v);
    out[((size_t)b * Nn + n) * 8 + k] = v;   // fully coalesced
}

extern "C" void kernel_launch(void* const* d_in, const int* in_sizes, int n_in,
                              void* d_out, int out_size, void* d_ws, size_t ws_size,
                              hipStream_t stream) {
    const float* batch  = (const float*)d_in[0];
    const float* points = (const float*)d_in[1];
    const int*   neigh  = (const int*)d_in[2];
    const float* W1     = (const float*)d_in[3];
    const float* b1     = (const float*)d_in[4];
    const float* W2     = (const float*)d_in[5];
    const float* b2     = (const float*)d_in[6];
    const float* W3     = (const float*)d_in[7];
    const float* b3     = (const float*)d_in[8];
    const float* Wlin   = (const float*)d_in[9];
    float* out = (float*)d_out;

    unsigned char* ws = (unsigned char*)d_ws;
    u32* cnt    = (u32*)(ws + CNT_OFF);
    u32* rowptr = (u32*)(ws + ROWPTR_OFF);
    u32* fill   = (u32*)(ws + FILL_OFF);
    u32* bsum   = (u32*)(ws + BSUM_OFF);
    u32* pairs  = (u32*)(ws + PAIRS_OFF);
    u16* msg    = (u16*)(ws + MSG_OFF);
    u32* pbf    = (u32*)(ws + PBF_OFF);
    u16* bbf    = (u16*)(ws + BBF_OFF);
    if (ws_size < WS_NEEDED) return;
    const int use_cvt = (ws_size >= WS_CVT);

    const dim3 b256(256);
    const dim3 gE((En + 255) / 256);
    const dim3 gEdge((En / 64 + 3) / 4);     // 3907 blocks, 4 waves x 64 slots
    const dim3 gN((Nn + 255) / 256);         // 196 (<= 256 for scan2)
    const dim3 gGather((Nn + 31) / 32);
    const dim3 gCvt((Bn * Nn + 255) / 256);  // 782

    hipMemsetAsync(cnt, 0, Nn * sizeof(u32), stream);
    gno_init_weights<<<dim3(41), b256, 0, stream>>>(W1, b1, W2, b2, W3, b3, ws);
    if (use_cvt)
        gno_cvt<<<gCvt, b256, 0, stream>>>(batch, points, pbf, bbf);
    gno_hist<<<gE, b256, 0, stream>>>(neigh, cnt);
    gno_scan1<<<gN, b256, 0, stream>>>(cnt, rowptr, bsum);
    gno_scan2<<<dim3(1), b256, 0, stream>>>(bsum, (int)gN.x);
    gno_scan3<<<gN, b256, 0, stream>>>(rowptr, bsum, fill);
    gno_slot<<<gE, b256, 0, stream>>>(neigh, fill, pairs);
    for (int b = 0; b < Bn; ++b) {
        if (use_cvt)
            gno_edge_mfma<1><<<gEdge, b256, 0, stream>>>(batch, points, pairs, ws, b, msg, pbf, bbf);
        else
            gno_edge_mfma<0><<<gEdge, b256, 0, stream>>>(batch, points, pairs, ws, b, msg, pbf, bbf);
        gno_gather_out<<<gGather, b256, 0, stream>>>(batch, Wlin, msg, rowptr, cnt, out, b);
    }
}

// Round 17
// 306.877 us; speedup vs baseline: 1.4022x; 1.1535x over previous
//
#include <hip/hip_runtime.h>

#define Bn 4
#define Nn 50000
#define En 1000000
#define FOUT 8

typedef unsigned int u32;
typedef unsigned short u16;
typedef __attribute__((ext_vector_type(8))) short bf16x8;
typedef __attribute__((ext_vector_type(4))) float f32x4;
typedef __attribute__((ext_vector_type(4))) int i32x4;

#define TANH_C 2.8853900817779268f   // 2*log2(e)

// ---- ws layout (bytes) ----
#define BLOB_BYTES 24576
#define W1T_OFF 0       // [64 q][32 k] bf16 (k padded 20->32)
#define W2T_OFF 4096    // [64 q][64 k] bf16
#define W3T_OFF 12288   // [64 c][64 k] bf16
#define B1_OFF 20480    // f32[64] sigma-permuted (unused by edge now; kept for init symmetry)
#define B2_OFF 20736
#define B3_OFF 20992
#define BSUM_OFF 21248  // u32[256]
#define B1C_OFF 22528   // f32[64]: TANH_C * b1[PERM(q)]  (bias folded into tanh exp)
#define B2C_OFF 22784   // f32[64]: TANH_C * b2[PERM(q)]

#define CNT_OFF    24576
#define ROWPTR_OFF 224576
#define FILL_OFF   424704                        // (free; fill no longer used)
#define PAIRS_OFF  624768                        // u32[En]: src | dst<<16  (Nn < 2^16)
#define MSG_OFF    4624768                       // bf16[En*8]; first 2MB doubles as rank[] pre-edge
#define RANK_OFF   MSG_OFF                       // u16[En] -- consumed by slot BEFORE msg written
#define WS_NEEDED (MSG_OFF + (size_t)En * FOUT * 2)   // 20,624,768 B (proven)
// bf16-precvt extension: packed points + bf16 batch
#define PBF_OFF    20624768                      // u32[Nn]
#define BBF_OFF    20824768                      // u16[Bn*Nn*8]
#define WS_CVT     (BBF_OFF + (size_t)Bn * Nn * FOUT * 2)   // 24,024,768 B

// tanh with bias folded: tanh(acc + b) = 1 - 2*rcp(exp2(acc*C + C*b) + 1)
__device__ __forceinline__ float fast_tanh_b(float acc, float cb) {
    float e = __builtin_amdgcn_exp2f(fmaf(acc, TANH_C, cb));
    return 1.0f - 2.0f * __builtin_amdgcn_rcpf(e + 1.0f);
}
__device__ __forceinline__ u32 pkbf(float lo, float hi) {
    u32 r;
    asm("v_cvt_pk_bf16_f32 %0, %1, %2" : "=v"(r) : "v"(lo), "v"(hi));
    return r;
}
__device__ __forceinline__ float bflo(u32 u) { return __builtin_bit_cast(float, u << 16); }
__device__ __forceinline__ float bfhi(u32 u) { return __builtin_bit_cast(float, u & 0xffff0000u); }
__device__ __forceinline__ u16 f2bf(float x) {
    u32 u = __builtin_bit_cast(u32, x);
    return (u16)((u + 0x7fff + ((u >> 16) & 1)) >> 16);
}
// sigma-permutation of MLP hidden channels (HW-verified rounds 4-16)
__device__ __forceinline__ int PERM_Q(int q) {
    int mi = q >> 4, g = (q >> 2) & 3, r = q & 3;
    return ((mi >> 1) << 5) | (g << 3) | ((mi & 1) << 2) | r;
}

__global__ void gno_init_weights(const float* __restrict__ W1, const float* __restrict__ b1,
                                 const float* __restrict__ W2, const float* __restrict__ b2,
                                 const float* __restrict__ W3, const float* __restrict__ b3,
                                 unsigned char* __restrict__ blob)
{
    int idx = blockIdx.x * 256 + threadIdx.x;
    if (idx < 2048) {
        int q = idx >> 5, k = idx & 31;
        float v = (k < 20) ? W1[k * 64 + PERM_Q(q)] : 0.0f;
        *(u16*)(blob + W1T_OFF + q * 64 + 2 * k) = f2bf(v);
    } else if (idx < 6144) {
        int j = idx - 2048, q = j >> 6, k = j & 63;
        *(u16*)(blob + W2T_OFF + q * 128 + 2 * k) = f2bf(W2[k * 64 + PERM_Q(q)]);
    } else if (idx < 10240) {
        int j = idx - 6144, c = j >> 6, k = j & 63;
        *(u16*)(blob + W3T_OFF + c * 128 + 2 * k) = f2bf(W3[k * 64 + c]);
    } else if (idx < 10304) {
        int q = idx - 10240;
        *(float*)(blob + B1_OFF + q * 4) = b1[PERM_Q(q)];
        *(float*)(blob + B1C_OFF + q * 4) = TANH_C * b1[PERM_Q(q)];
    } else if (idx < 10368) {
        int q = idx - 10304;
        *(float*)(blob + B2_OFF + q * 4) = b2[PERM_Q(q)];
        *(float*)(blob + B2C_OFF + q * 4) = TANH_C * b2[PERM_Q(q)];
    } else if (idx < 10432) { int c = idx - 10368; *(float*)(blob + B3_OFF + c * 4) = b3[c]; }
}

// ---- bf16 pre-conversion ----
__global__ void gno_cvt(const float* __restrict__ batch, const float* __restrict__ points,
                        u32* __restrict__ pbf, u16* __restrict__ bbf)
{
    const int t = blockIdx.x * 256 + threadIdx.x;
    if (t < Bn * Nn) {
        const float4* bp = (const float4*)(batch + (size_t)t * 8);
        const float4 a = bp[0], c = bp[1];
        *(uint4*)(bbf + (size_t)t * 8) =
            make_uint4(pkbf(a.x, a.y), pkbf(a.z, a.w), pkbf(c.x, c.y), pkbf(c.z, c.w));
    }
    if (t < Nn) {
        const float2 pp = *(const float2*)(points + 2 * (size_t)t);
        pbf[t] = pkbf(pp.x, pp.y);
    }
}

// ---- CSR build: rank-fused (round 17) ----
// pass 1: histogram WITH per-edge rank capture (coalesced u16 store into msg region)
__global__ void gno_hist_rank(const int* __restrict__ neigh, u32* __restrict__ cnt,
                              u16* __restrict__ rank) {
    const int e = blockIdx.x * 256 + threadIdx.x;
    if (e < En) rank[e] = (u16)atomicAdd(&cnt[neigh[e]], 1u);
}
__global__ __launch_bounds__(256) void gno_scan1(const u32* __restrict__ cnt,
                                                 u32* __restrict__ rowptr,
                                                 u32* __restrict__ bsum)
{
    __shared__ u32 wtot[4];
    const int tid = threadIdx.x, lane = tid & 63, w = tid >> 6;
    const int n = blockIdx.x * 256 + tid;
    const u32 c = (n < Nn) ? cnt[n] : 0u;
    u32 inc = c;
    #pragma unroll
    for (int off = 1; off < 64; off <<= 1) {
        u32 x = __shfl_up(inc, off, 64);
        if (lane >= off) inc += x;
    }
    if (lane == 63) wtot[w] = inc;
    __syncthreads();
    u32 woff = 0;
    for (int i = 0; i < w; ++i) woff += wtot[i];
    if (n < Nn) rowptr[n] = woff + inc - c;
    if (tid == 255) bsum[blockIdx.x] = woff + inc;
}
__global__ __launch_bounds__(256) void gno_scan2(u32* __restrict__ bsum, const int nb)
{
    __shared__ u32 wtot[4];
    const int tid = threadIdx.x, lane = tid & 63, w = tid >> 6;
    const u32 c = (tid < nb) ? bsum[tid] : 0u;
    u32 inc = c;
    #pragma unroll
    for (int off = 1; off < 64; off <<= 1) {
        u32 x = __shfl_up(inc, off, 64);
        if (lane >= off) inc += x;
    }
    if (lane == 63) wtot[w] = inc;
    __syncthreads();
    u32 woff = 0;
    for (int i = 0; i < w; ++i) woff += wtot[i];
    if (tid < nb) bsum[tid] = woff + inc - c;
}
__global__ __launch_bounds__(256) void gno_scan3(u32* __restrict__ rowptr,
                                                 const u32* __restrict__ bsum)
{
    const int n = blockIdx.x * 256 + threadIdx.x;
    if (n < Nn) rowptr[n] += bsum[blockIdx.x];
    if (n == 0) rowptr[Nn] = En;
}
// pass 2: slot = rowptr[dn] + rank[e]; NO atomics (round 17)
__global__ void gno_slot(const int* __restrict__ neigh, const u32* __restrict__ rowptr,
                         const u16* __restrict__ rank, u32* __restrict__ pairs) {
    const int e = blockIdx.x * 256 + threadIdx.x;
    if (e < En) {
        const int dn = neigh[e];
        const int sn = neigh[En + e];
        const u32 s = rowptr[dn] + rank[e];
        pairs[s] = (u32)sn | ((u32)dn << 16);
    }
}

// ---- edge MLP over CSR slot order: 4 waves x 64 slots per block ----
// PERMANENT (256,4): spill ledger r8/r10/r12/r14. Round 17: L1/L2 accumulators
// start at ZERO (LLVM folds inline-0 MFMA src2) and bias enters via the tanh
// exponent (exact same arithmetic) -> -128 acc-init movs/thread.
template<int CVT>
__global__ __launch_bounds__(256, 4) void gno_edge_mfma(
    const float* __restrict__ batch, const float* __restrict__ points,
    const u32* __restrict__ pairs, const unsigned char* __restrict__ wblob,
    const int b, u16* __restrict__ msg,
    const u32* __restrict__ pbf, const u16* __restrict__ bbf)
{
    __shared__ __align__(128) unsigned char feat_lds[4 * 64 * 64];  // [w][e][32 bf16]
    __shared__ __align__(16) unsigned char by_lds[4 * 64 * 16];     // [w][e][8 bf16]

    const int tid = threadIdx.x;
    const int lane = tid & 63;
    const int w = tid >> 6;
    const int s0 = (blockIdx.x * 4 + w) * 64;
    if (s0 >= En) return;                  // wave-uniform tail guard; no barriers
    const int t = lane & 15;
    const int g = lane >> 4;

    // stage feat: all 64 lanes, one slot each (wave-private region, in-wave ordering)
    {
        const u32 p = pairs[s0 + lane];
        const int sn = (int)(p & 0xffffu);
        const int dn = (int)(p >> 16);
        unsigned char* fb = feat_lds + w * 4096;
        const int base = lane << 6;
        const int sw = (lane & 7) << 4;
        if constexpr (CVT) {
            const u32 pspk = pbf[sn];
            const u32 pdpk = pbf[dn];
            const uint4 bx = *(const uint4*)(bbf + ((size_t)b * Nn + sn) * 8);
            const uint4 by = *(const uint4*)(bbf + ((size_t)b * Nn + dn) * 8);
            *(uint4*)(fb + ((base + 0)  ^ sw)) = make_uint4(pspk, pdpk, bx.x, bx.y);
            *(uint4*)(fb + ((base + 16) ^ sw)) = make_uint4(bx.z, bx.w, by.x, by.y);
            *(uint4*)(fb + ((base + 32) ^ sw)) = make_uint4(by.z, by.w, 0u, 0u);
            *(uint4*)(fb + ((base + 48) ^ sw)) = make_uint4(0u, 0u, 0u, 0u);
            *(uint4*)(by_lds + w * 1024 + lane * 16) = by;
        } else {
            const float2 ps = *(const float2*)(points + 2 * (size_t)sn);
            const float2 pd = *(const float2*)(points + 2 * (size_t)dn);
            const float4* bxp = (const float4*)(batch + ((size_t)b * Nn + sn) * 8);
            const float4 bx0 = bxp[0], bx1 = bxp[1];
            const float4* byp = (const float4*)(batch + ((size_t)b * Nn + dn) * 8);
            const float4 by0 = byp[0], by1 = byp[1];
            *(uint4*)(fb + ((base + 0)  ^ sw)) = make_uint4(pkbf(ps.x, ps.y), pkbf(pd.x, pd.y),
                                                            pkbf(bx0.x, bx0.y), pkbf(bx0.z, bx0.w));
            *(uint4*)(fb + ((base + 16) ^ sw)) = make_uint4(pkbf(bx1.x, bx1.y), pkbf(bx1.z, bx1.w),
                                                            pkbf(by0.x, by0.y), pkbf(by0.z, by0.w));
            *(uint4*)(fb + ((base + 32) ^ sw)) = make_uint4(pkbf(by1.x, by1.y), pkbf(by1.z, by1.w), 0u, 0u);
            *(uint4*)(fb + ((base + 48) ^ sw)) = make_uint4(0u, 0u, 0u, 0u);
            *(uint4*)(by_lds + w * 1024 + lane * 16) = make_uint4(pkbf(by0.x, by0.y), pkbf(by0.z, by0.w),
                                                                  pkbf(by1.x, by1.y), pkbf(by1.z, by1.w));
        }
    }

    u32 pk1[4][4][2];   // L1 outputs, packed bf16 (sigma: lane-held == lane-needed)

    // ----- L1 (K=32), M in two halves; acc from 0, bias in tanh exponent -----
    {
        bf16x8 bfr[4];
        #pragma unroll
        for (int nj = 0; nj < 4; ++nj) {
            const int row = nj * 16 + t;
            bfr[nj] = *(const bf16x8*)(feat_lds + w * 4096 + ((row * 64 + (g << 4)) ^ ((row & 7) << 4)));
        }
        #pragma unroll
        for (int h = 0; h < 2; ++h) {
            f32x4 acc[2][4] = {};
            bf16x8 afr[2];
            f32x4 cbv[2];
            #pragma unroll
            for (int d = 0; d < 2; ++d) {
                const int mi = 2 * h + d;
                cbv[d] = *(const f32x4*)(wblob + B1C_OFF + (mi * 16 + g * 4) * 4);
                afr[d] = *(const bf16x8*)(wblob + W1T_OFF + (mi * 16 + t) * 64 + (g << 4));
            }
            #pragma unroll
            for (int d = 0; d < 2; ++d)
                #pragma unroll
                for (int nj = 0; nj < 4; ++nj)
                    acc[d][nj] = __builtin_amdgcn_mfma_f32_16x16x32_bf16(afr[d], bfr[nj], acc[d][nj], 0, 0, 0);
            #pragma unroll
            for (int d = 0; d < 2; ++d)
                #pragma unroll
                for (int nj = 0; nj < 4; ++nj) {
                    pk1[2 * h + d][nj][0] = pkbf(fast_tanh_b(acc[d][nj][0], cbv[d][0]),
                                                 fast_tanh_b(acc[d][nj][1], cbv[d][1]));
                    pk1[2 * h + d][nj][1] = pkbf(fast_tanh_b(acc[d][nj][2], cbv[d][2]),
                                                 fast_tanh_b(acc[d][nj][3], cbv[d][3]));
                }
        }
    }

    // ----- L2 (K=64), M in two halves; acc from 0, bias in tanh exponent -----
    u32 pk2[4][4][2];
    #pragma unroll
    for (int h = 0; h < 2; ++h) {
        f32x4 acc[2][4] = {};
        f32x4 cbv[2];
        #pragma unroll
        for (int d = 0; d < 2; ++d)
            cbv[d] = *(const f32x4*)(wblob + B2C_OFF + ((2 * h + d) * 16 + g * 4) * 4);
        #pragma unroll
        for (int kt = 0; kt < 2; ++kt) {
            bf16x8 afr[2];
            #pragma unroll
            for (int d = 0; d < 2; ++d)
                afr[d] = *(const bf16x8*)(wblob + W2T_OFF + ((2 * h + d) * 16 + t) * 128 + kt * 64 + (g << 4));
            #pragma unroll
            for (int nj = 0; nj < 4; ++nj) {
                const i32x4 bi = { (int)pk1[2 * kt][nj][0], (int)pk1[2 * kt][nj][1],
                                   (int)pk1[2 * kt + 1][nj][0], (int)pk1[2 * kt + 1][nj][1] };
                const bf16x8 bf = __builtin_bit_cast(bf16x8, bi);
                #pragma unroll
                for (int d = 0; d < 2; ++d)
                    acc[d][nj] = __builtin_amdgcn_mfma_f32_16x16x32_bf16(afr[d], bf, acc[d][nj], 0, 0, 0);
            }
        }
        #pragma unroll
        for (int d = 0; d < 2; ++d)
            #pragma unroll
            for (int nj = 0; nj < 4; ++nj) {
                pk2[2 * h + d][nj][0] = pkbf(fast_tanh_b(acc[d][nj][0], cbv[d][0]),
                                             fast_tanh_b(acc[d][nj][1], cbv[d][1]));
                pk2[2 * h + d][nj][1] = pkbf(fast_tanh_b(acc[d][nj][2], cbv[d][2]),
                                             fast_tanh_b(acc[d][nj][3], cbv[d][3]));
            }
    }

    // ----- L3 (K=64) + fused epilogue, M in two halves (bias stays as acc init) -----
    const int jhalf = g & 1;
    #pragma unroll
    for (int h = 0; h < 2; ++h) {
        f32x4 acc[2][4];
        #pragma unroll
        for (int d = 0; d < 2; ++d) {
            const int mi = 2 * h + d;
            const f32x4 bv = *(const f32x4*)(wblob + B3_OFF + (mi * 16 + g * 4) * 4);
            #pragma unroll
            for (int nj = 0; nj < 4; ++nj) acc[d][nj] = bv;
        }
        #pragma unroll
        for (int kt = 0; kt < 2; ++kt) {
            bf16x8 afr[2];
            #pragma unroll
            for (int d = 0; d < 2; ++d)
                afr[d] = *(const bf16x8*)(wblob + W3T_OFF + ((2 * h + d) * 16 + t) * 128 + kt * 64 + (g << 4));
            #pragma unroll
            for (int nj = 0; nj < 4; ++nj) {
                const i32x4 bi = { (int)pk2[2 * kt][nj][0], (int)pk2[2 * kt][nj][1],
                                   (int)pk2[2 * kt + 1][nj][0], (int)pk2[2 * kt + 1][nj][1] };
                const bf16x8 bf = __builtin_bit_cast(bf16x8, bi);
                #pragma unroll
                for (int d = 0; d < 2; ++d)
                    acc[d][nj] = __builtin_amdgcn_mfma_f32_16x16x32_bf16(afr[d], bf, acc[d][nj], 0, 0, 0);
            }
        }
        // epilogue for channels 4h..4h+3: i = 2*(2h+d)+(g>>1), j = jhalf*4+r
        #pragma unroll
        for (int nj = 0; nj < 4; ++nj) {
            const int el = nj * 16 + t;
            const uint2 byw = *(const uint2*)(by_lds + w * 1024 + el * 16 + jhalf * 8);
            const float f0 = bflo(byw.x), f1 = bfhi(byw.x), f2 = bflo(byw.y), f3 = bfhi(byw.y);
            u32 pks[2];
            #pragma unroll
            for (int d = 0; d < 2; ++d) {
                const f32x4 a = acc[d][nj];
                float p = fmaf(a[0], f0, fmaf(a[1], f1, fmaf(a[2], f2, a[3] * f3)));
                const float m  = p + __shfl_xor(p, 16, 64);   // full dot
                const float mo = __shfl_xor(m, 32, 64);       // partner channel
                pks[d] = pkbf(m, mo);                          // (2mi, 2mi+1) on g==0
            }
            if (g == 0)
                *(uint2*)(msg + (size_t)(s0 + el) * 8 + h * 4) = make_uint2(pks[0], pks[1]);
        }
    }
}

// ---- fused CSR gather + finalize: 8 lanes per node, coalesced uint4 slot reads ----
__global__ __launch_bounds__(256) void gno_gather_out(
    const float* __restrict__ batch, const float* __restrict__ Wlin,
    const u16* __restrict__ msg, const u32* __restrict__ rowptr,
    const u32* __restrict__ cnt, float* __restrict__ out, const int b)
{
    const int tid = threadIdx.x;
    const int n = blockIdx.x * 32 + (tid >> 3);
    const int k = tid & 7;
    if (n >= Nn) return;
    const u32 dg = cnt[n];
    const u32 j0 = rowptr[n];
    float acc[8] = {0, 0, 0, 0, 0, 0, 0, 0};
    for (u32 j = j0 + k; j < j0 + dg; j += 8) {
        const uint4 m = *(const uint4*)(msg + (size_t)j * 8);
        acc[0] += bflo(m.x); acc[1] += bfhi(m.x);
        acc[2] += bflo(m.y); acc[3] += bfhi(m.y);
        acc[4] += bflo(m.z); acc[5] += bfhi(m.z);
        acc[6] += bflo(m.w); acc[7] += bfhi(m.w);
    }
    #pragma unroll
    for (int s = 1; s < 8; s <<= 1) {
        #pragma unroll
        for (int c = 0; c < 8; ++c) acc[c] += __shfl_xor(acc[c], s, 64);
    }
    float v = acc[k] * __builtin_amdgcn_rcpf((float)dg + 1.0f);
    const float* br = batch + ((size_t)b * Nn + n) * 8;
    #pragma unroll
    for (int j = 0; j < 8; ++j) v = fmaf(br[j], Wlin[j * FOUT + k], v);
    out[((size_t)b * Nn + n) * 8 + k] = v;   // fully coalesced
}

extern "C" void kernel_launch(void* const* d_in, const int* in_sizes, int n_in,
                              void* d_out, int out_size, void* d_ws, size_t ws_size,
                              hipStream_t stream) {
    const float* batch  = (const float*)d_in[0];
    const float* points = (const float*)d_in[1];
    const int*   neigh  = (const int*)d_in[2];
    const float* W1     = (const float*)d_in[3];
    const float* b1     = (const float*)d_in[4];
    const float* W2     = (const float*)d_in[5];
    const float* b2     = (const float*)d_in[6];
    const float* W3     = (const float*)d_in[7];
    const float* b3     = (const float*)d_in[8];
    const float* Wlin   = (const float*)d_in[9];
    float* out = (float*)d_out;

    unsigned char* ws = (unsigned char*)d_ws;
    u32* cnt    = (u32*)(ws + CNT_OFF);
    u32* rowptr = (u32*)(ws + ROWPTR_OFF);
    u32* bsum   = (u32*)(ws + BSUM_OFF);
    u32* pairs  = (u32*)(ws + PAIRS_OFF);
    u16* rank   = (u16*)(ws + RANK_OFF);     // aliases msg; consumed before msg written
    u16* msg    = (u16*)(ws + MSG_OFF);
    u32* pbf    = (u32*)(ws + PBF_OFF);
    u16* bbf    = (u16*)(ws + BBF_OFF);
    if (ws_size < WS_NEEDED) return;
    const int use_cvt = (ws_size >= WS_CVT);

    const dim3 b256(256);
    const dim3 gE((En + 255) / 256);
    const dim3 gEdge((En / 64 + 3) / 4);     // 3907 blocks, 4 waves x 64 slots
    const dim3 gN((Nn + 255) / 256);         // 196 (<= 256 for scan2)
    const dim3 gGather((Nn + 31) / 32);
    const dim3 gCvt((Bn * Nn + 255) / 256);

    hipMemsetAsync(cnt, 0, Nn * sizeof(u32), stream);
    gno_init_weights<<<dim3(41), b256, 0, stream>>>(W1, b1, W2, b2, W3, b3, ws);
    if (use_cvt)
        gno_cvt<<<gCvt, b256, 0, stream>>>(batch, points, pbf, bbf);
    gno_hist_rank<<<gE, b256, 0, stream>>>(neigh, cnt, rank);
    gno_scan1<<<gN, b256, 0, stream>>>(cnt, rowptr, bsum);
    gno_scan2<<<dim3(1), b256, 0, stream>>>(bsum, (int)gN.x);
    gno_scan3<<<gN, b256, 0, stream>>>(rowptr, bsum);
    gno_slot<<<gE, b256, 0, stream>>>(neigh, rowptr, rank, pairs);
    for (int b = 0; b < Bn; ++b) {
        if (use_cvt)
            gno_edge_mfma<1><<<gEdge, b256, 0, stream>>>(batch, points, pairs, ws, b, msg, pbf, bbf);
        else
            gno_edge_mfma<0><<<gEdge, b256, 0, stream>>>(batch, points, pairs, ws, b, msg, pbf, bbf);
        gno_gather_out<<<gGather, b256, 0, stream>>>(batch, Wlin, msg, rowptr, cnt, out, b);
    }
}

// Round 19
// 281.180 us; speedup vs baseline: 1.5304x; 1.0914x over previous
//
#include <hip/hip_runtime.h>

#define Bn 4
#define Nn 50000
#define En 1000000
#define FOUT 8

typedef unsigned int u32;
typedef unsigned short u16;
typedef __attribute__((ext_vector_type(8))) short bf16x8;
typedef __attribute__((ext_vector_type(4))) float f32x4;
typedef __attribute__((ext_vector_type(4))) int i32x4;

#define TANH_C 2.8853900817779268f   // 2*log2(e)

// ---- ws layout (bytes) ----
#define BLOB_BYTES 24576
#define W1T_OFF 0       // [64 q][32 k] bf16 (k padded 20->32)
#define W2T_OFF 4096    // [64 q][64 k] bf16
#define W3T_OFF 12288   // [64 c][64 k] bf16
#define B1_OFF 20480
#define B2_OFF 20736
#define B3_OFF 20992
#define BSUM_OFF 21248  // u32[256]
#define B1C_OFF 22528   // f32[64]: TANH_C * b1[PERM(q)]
#define B2C_OFF 22784   // f32[64]: TANH_C * b2[PERM(q)]

#define CNT_OFF    24576
#define ROWPTR_OFF 224576
#define PAIRS_OFF  624768                        // u32[En]: src | dst<<16
#define MSG_OFF    4624768                       // bf16[En*8] (tier<2) / 4 buffers (tier2)
#define RANK_OFF   MSG_OFF                       // u16[En], consumed before msg written
#define WS_NEEDED (MSG_OFF + (size_t)En * FOUT * 2)            // 20,624,768 (proven)
// tier1: cvt buffers after single msg
#define PBF_OFF    20624768
#define BBF_OFF    20824768
#define WS_CVT     (BBF_OFF + (size_t)Bn * Nn * FOUT * 2)      // 24,024,768
// tier2: 4 msg buffers + cvt
#define MSTRIDE    ((size_t)En * FOUT)                          // u16 units per batch
#define PBF4_OFF   (MSG_OFF + (size_t)Bn * En * FOUT * 2)       // 68,624,768
#define BBF4_OFF   (PBF4_OFF + (size_t)Nn * 4)                  // 68,824,768
#define WS_4       (BBF4_OFF + (size_t)Bn * Nn * FOUT * 2)      // 72,024,768

__device__ __forceinline__ float fast_tanh_b(float acc, float cb) {
    float e = __builtin_amdgcn_exp2f(fmaf(acc, TANH_C, cb));
    return 1.0f - 2.0f * __builtin_amdgcn_rcpf(e + 1.0f);
}
__device__ __forceinline__ u32 pkbf(float lo, float hi) {
    u32 r;
    asm("v_cvt_pk_bf16_f32 %0, %1, %2" : "=v"(r) : "v"(lo), "v"(hi));
    return r;
}
__device__ __forceinline__ float bflo(u32 u) { return __builtin_bit_cast(float, u << 16); }
__device__ __forceinline__ float bfhi(u32 u) { return __builtin_bit_cast(float, u & 0xffff0000u); }
__device__ __forceinline__ u16 f2bf(float x) {
    u32 u = __builtin_bit_cast(u32, x);
    return (u16)((u + 0x7fff + ((u >> 16) & 1)) >> 16);
}
// sigma-permutation of MLP hidden channels (HW-verified rounds 4-17)
__device__ __forceinline__ int PERM_Q(int q) {
    int mi = q >> 4, g = (q >> 2) & 3, r = q & 3;
    return ((mi >> 1) << 5) | (g << 3) | ((mi & 1) << 2) | r;
}

__global__ void gno_init_weights(const float* __restrict__ W1, const float* __restrict__ b1,
                                 const float* __restrict__ W2, const float* __restrict__ b2,
                                 const float* __restrict__ W3, const float* __restrict__ b3,
                                 unsigned char* __restrict__ blob)
{
    int idx = blockIdx.x * 256 + threadIdx.x;
    if (idx < 2048) {
        int q = idx >> 5, k = idx & 31;
        float v = (k < 20) ? W1[k * 64 + PERM_Q(q)] : 0.0f;
        *(u16*)(blob + W1T_OFF + q * 64 + 2 * k) = f2bf(v);
    } else if (idx < 6144) {
        int j = idx - 2048, q = j >> 6, k = j & 63;
        *(u16*)(blob + W2T_OFF + q * 128 + 2 * k) = f2bf(W2[k * 64 + PERM_Q(q)]);
    } else if (idx < 10240) {
        int j = idx - 6144, c = j >> 6, k = j & 63;
        *(u16*)(blob + W3T_OFF + c * 128 + 2 * k) = f2bf(W3[k * 64 + c]);
    } else if (idx < 10304) {
        int q = idx - 10240;
        *(float*)(blob + B1_OFF + q * 4) = b1[PERM_Q(q)];
        *(float*)(blob + B1C_OFF + q * 4) = TANH_C * b1[PERM_Q(q)];
    } else if (idx < 10368) {
        int q = idx - 10304;
        *(float*)(blob + B2_OFF + q * 4) = b2[PERM_Q(q)];
        *(float*)(blob + B2C_OFF + q * 4) = TANH_C * b2[PERM_Q(q)];
    } else if (idx < 10432) { int c = idx - 10368; *(float*)(blob + B3_OFF + c * 4) = b3[c]; }
}

// ---- bf16 pre-conversion ----
__global__ void gno_cvt(const float* __restrict__ batch, const float* __restrict__ points,
                        u32* __restrict__ pbf, u16* __restrict__ bbf)
{
    const int t = blockIdx.x * 256 + threadIdx.x;
    if (t < Bn * Nn) {
        const float4* bp = (const float4*)(batch + (size_t)t * 8);
        const float4 a = bp[0], c = bp[1];
        *(uint4*)(bbf + (size_t)t * 8) =
            make_uint4(pkbf(a.x, a.y), pkbf(a.z, a.w), pkbf(c.x, c.y), pkbf(c.z, c.w));
    }
    if (t < Nn) {
        const float2 pp = *(const float2*)(points + 2 * (size_t)t);
        pbf[t] = pkbf(pp.x, pp.y);
    }
}

// ---- CSR build: rank-fused (proven round 17) ----
__global__ void gno_hist_rank(const int* __restrict__ neigh, u32* __restrict__ cnt,
                              u16* __restrict__ rank) {
    const int e = blockIdx.x * 256 + threadIdx.x;
    if (e < En) rank[e] = (u16)atomicAdd(&cnt[neigh[e]], 1u);
}
__global__ __launch_bounds__(256) void gno_scan1(const u32* __restrict__ cnt,
                                                 u32* __restrict__ rowptr,
                                                 u32* __restrict__ bsum)
{
    __shared__ u32 wtot[4];
    const int tid = threadIdx.x, lane = tid & 63, w = tid >> 6;
    const int n = blockIdx.x * 256 + tid;
    const u32 c = (n < Nn) ? cnt[n] : 0u;
    u32 inc = c;
    #pragma unroll
    for (int off = 1; off < 64; off <<= 1) {
        u32 x = __shfl_up(inc, off, 64);
        if (lane >= off) inc += x;
    }
    if (lane == 63) wtot[w] = inc;
    __syncthreads();
    u32 woff = 0;
    for (int i = 0; i < w; ++i) woff += wtot[i];
    if (n < Nn) rowptr[n] = woff + inc - c;
    if (tid == 255) bsum[blockIdx.x] = woff + inc;
}
__global__ __launch_bounds__(256) void gno_scan2(u32* __restrict__ bsum, const int nb)
{
    __shared__ u32 wtot[4];
    const int tid = threadIdx.x, lane = tid & 63, w = tid >> 6;
    const u32 c = (tid < nb) ? bsum[tid] : 0u;
    u32 inc = c;
    #pragma unroll
    for (int off = 1; off < 64; off <<= 1) {
        u32 x = __shfl_up(inc, off, 64);
        if (lane >= off) inc += x;
    }
    if (lane == 63) wtot[w] = inc;
    __syncthreads();
    u32 woff = 0;
    for (int i = 0; i < w; ++i) woff += wtot[i];
    if (tid < nb) bsum[tid] = woff + inc - c;
}
__global__ __launch_bounds__(256) void gno_scan3(u32* __restrict__ rowptr,
                                                 const u32* __restrict__ bsum)
{
    const int n = blockIdx.x * 256 + threadIdx.x;
    if (n < Nn) rowptr[n] += bsum[blockIdx.x];
    if (n == 0) rowptr[Nn] = En;
}
__global__ void gno_slot(const int* __restrict__ neigh, const u32* __restrict__ rowptr,
                         const u16* __restrict__ rank, u32* __restrict__ pairs) {
    const int e = blockIdx.x * 256 + threadIdx.x;
    if (e < En) {
        const int dn = neigh[e];
        const int sn = neigh[En + e];
        const u32 s = rowptr[dn] + rank[e];
        pairs[s] = (u32)sn | ((u32)dn << 16);
    }
}

// ---- edge MLP over CSR slot order: 4 waves x 64 slots per block ----
// PERMANENT (256,4): spill ledger r8/r10/r12/r14. Round 18: by read from
// feat_lds (by_lds dropped, -4KB LDS); optional grid.y batch fusion (bsel<0).
template<int CVT>
__global__ __launch_bounds__(256, 4) void gno_edge_mfma(
    const float* __restrict__ batch, const float* __restrict__ points,
    const u32* __restrict__ pairs, const unsigned char* __restrict__ wblob,
    const int bsel, u16* __restrict__ msg0, const size_t mstride,
    const u32* __restrict__ pbf, const u16* __restrict__ bbf)
{
    __shared__ __align__(128) unsigned char feat_lds[4 * 64 * 64];  // [w][e][32 bf16]

    const int tid = threadIdx.x;
    const int lane = tid & 63;
    const int w = tid >> 6;
    const int s0 = (blockIdx.x * 4 + w) * 64;
    if (s0 >= En) return;                  // wave-uniform tail guard; no barriers
    const int t = lane & 15;
    const int g = lane >> 4;
    const int b = (bsel >= 0) ? bsel : (int)blockIdx.y;
    u16* __restrict__ msg = msg0 + (size_t)b * mstride;
    unsigned char* fb = feat_lds + w * 4096;

    // stage feat: all 64 lanes, one slot each (wave-private region, in-wave ordering)
    {
        const u32 p = pairs[s0 + lane];
        const int sn = (int)(p & 0xffffu);
        const int dn = (int)(p >> 16);
        const int base = lane << 6;
        const int sw = (lane & 7) << 4;
        if constexpr (CVT) {
            const u32 pspk = pbf[sn];
            const u32 pdpk = pbf[dn];
            const uint4 bx = *(const uint4*)(bbf + ((size_t)b * Nn + sn) * 8);
            const uint4 by = *(const uint4*)(bbf + ((size_t)b * Nn + dn) * 8);
            *(uint4*)(fb + ((base + 0)  ^ sw)) = make_uint4(pspk, pdpk, bx.x, bx.y);
            *(uint4*)(fb + ((base + 16) ^ sw)) = make_uint4(bx.z, bx.w, by.x, by.y);
            *(uint4*)(fb + ((base + 32) ^ sw)) = make_uint4(by.z, by.w, 0u, 0u);
            *(uint4*)(fb + ((base + 48) ^ sw)) = make_uint4(0u, 0u, 0u, 0u);
        } else {
            const float2 ps = *(const float2*)(points + 2 * (size_t)sn);
            const float2 pd = *(const float2*)(points + 2 * (size_t)dn);
            const float4* bxp = (const float4*)(batch + ((size_t)b * Nn + sn) * 8);
            const float4 bx0 = bxp[0], bx1 = bxp[1];
            const float4* byp = (const float4*)(batch + ((size_t)b * Nn + dn) * 8);
            const float4 by0 = byp[0], by1 = byp[1];
            *(uint4*)(fb + ((base + 0)  ^ sw)) = make_uint4(pkbf(ps.x, ps.y), pkbf(pd.x, pd.y),
                                                            pkbf(bx0.x, bx0.y), pkbf(bx0.z, bx0.w));
            *(uint4*)(fb + ((base + 16) ^ sw)) = make_uint4(pkbf(bx1.x, bx1.y), pkbf(bx1.z, bx1.w),
                                                            pkbf(by0.x, by0.y), pkbf(by0.z, by0.w));
            *(uint4*)(fb + ((base + 32) ^ sw)) = make_uint4(pkbf(by1.x, by1.y), pkbf(by1.z, by1.w), 0u, 0u);
            *(uint4*)(fb + ((base + 48) ^ sw)) = make_uint4(0u, 0u, 0u, 0u);
        }
    }

    u32 pk1[4][4][2];   // L1 outputs, packed bf16 (sigma: lane-held == lane-needed)

    // ----- L1 (K=32), M in two halves; acc from 0, bias in tanh exponent -----
    {
        bf16x8 bfr[4];
        #pragma unroll
        for (int nj = 0; nj < 4; ++nj) {
            const int row = nj * 16 + t;
            bfr[nj] = *(const bf16x8*)(feat_lds + w * 4096 + ((row * 64 + (g << 4)) ^ ((row & 7) << 4)));
        }
        #pragma unroll
        for (int h = 0; h < 2; ++h) {
            f32x4 acc[2][4] = {};
            bf16x8 afr[2];
            f32x4 cbv[2];
            #pragma unroll
            for (int d = 0; d < 2; ++d) {
                const int mi = 2 * h + d;
                cbv[d] = *(const f32x4*)(wblob + B1C_OFF + (mi * 16 + g * 4) * 4);
                afr[d] = *(const bf16x8*)(wblob + W1T_OFF + (mi * 16 + t) * 64 + (g << 4));
            }
            #pragma unroll
            for (int d = 0; d < 2; ++d)
                #pragma unroll
                for (int nj = 0; nj < 4; ++nj)
                    acc[d][nj] = __builtin_amdgcn_mfma_f32_16x16x32_bf16(afr[d], bfr[nj], acc[d][nj], 0, 0, 0);
            #pragma unroll
            for (int d = 0; d < 2; ++d)
                #pragma unroll
                for (int nj = 0; nj < 4; ++nj) {
                    pk1[2 * h + d][nj][0] = pkbf(fast_tanh_b(acc[d][nj][0], cbv[d][0]),
                                                 fast_tanh_b(acc[d][nj][1], cbv[d][1]));
                    pk1[2 * h + d][nj][1] = pkbf(fast_tanh_b(acc[d][nj][2], cbv[d][2]),
                                                 fast_tanh_b(acc[d][nj][3], cbv[d][3]));
                }
        }
    }

    // ----- L2 (K=64), M in two halves; B-frags from pk1 registers -----
    u32 pk2[4][4][2];
    #pragma unroll
    for (int h = 0; h < 2; ++h) {
        f32x4 acc[2][4] = {};
        f32x4 cbv[2];
        #pragma unroll
        for (int d = 0; d < 2; ++d)
            cbv[d] = *(const f32x4*)(wblob + B2C_OFF + ((2 * h + d) * 16 + g * 4) * 4);
        #pragma unroll
        for (int kt = 0; kt < 2; ++kt) {
            bf16x8 afr[2];
            #pragma unroll
            for (int d = 0; d < 2; ++d)
                afr[d] = *(const bf16x8*)(wblob + W2T_OFF + ((2 * h + d) * 16 + t) * 128 + kt * 64 + (g << 4));
            #pragma unroll
            for (int nj = 0; nj < 4; ++nj) {
                const i32x4 bi = { (int)pk1[2 * kt][nj][0], (int)pk1[2 * kt][nj][1],
                                   (int)pk1[2 * kt + 1][nj][0], (int)pk1[2 * kt + 1][nj][1] };
                const bf16x8 bf = __builtin_bit_cast(bf16x8, bi);
                #pragma unroll
                for (int d = 0; d < 2; ++d)
                    acc[d][nj] = __builtin_amdgcn_mfma_f32_16x16x32_bf16(afr[d], bf, acc[d][nj], 0, 0, 0);
            }
        }
        #pragma unroll
        for (int d = 0; d < 2; ++d)
            #pragma unroll
            for (int nj = 0; nj < 4; ++nj) {
                pk2[2 * h + d][nj][0] = pkbf(fast_tanh_b(acc[d][nj][0], cbv[d][0]),
                                             fast_tanh_b(acc[d][nj][1], cbv[d][1]));
                pk2[2 * h + d][nj][1] = pkbf(fast_tanh_b(acc[d][nj][2], cbv[d][2]),
                                             fast_tanh_b(acc[d][nj][3], cbv[d][3]));
            }
    }

    // ----- L3 (K=64) + fused epilogue, M in two halves (bias stays as acc init) -----
    const int jhalf = g & 1;
    #pragma unroll
    for (int h = 0; h < 2; ++h) {
        f32x4 acc[2][4];
        #pragma unroll
        for (int d = 0; d < 2; ++d) {
            const int mi = 2 * h + d;
            const f32x4 bv = *(const f32x4*)(wblob + B3_OFF + (mi * 16 + g * 4) * 4);
            #pragma unroll
            for (int nj = 0; nj < 4; ++nj) acc[d][nj] = bv;
        }
        #pragma unroll
        for (int kt = 0; kt < 2; ++kt) {
            bf16x8 afr[2];
            #pragma unroll
            for (int d = 0; d < 2; ++d)
                afr[d] = *(const bf16x8*)(wblob + W3T_OFF + ((2 * h + d) * 16 + t) * 128 + kt * 64 + (g << 4));
            #pragma unroll
            for (int nj = 0; nj < 4; ++nj) {
                const i32x4 bi = { (int)pk2[2 * kt][nj][0], (int)pk2[2 * kt][nj][1],
                                   (int)pk2[2 * kt + 1][nj][0], (int)pk2[2 * kt + 1][nj][1] };
                const bf16x8 bf = __builtin_bit_cast(bf16x8, bi);
                #pragma unroll
                for (int d = 0; d < 2; ++d)
                    acc[d][nj] = __builtin_amdgcn_mfma_f32_16x16x32_bf16(afr[d], bf, acc[d][nj], 0, 0, 0);
            }
        }
        // epilogue for channels 4h..4h+3: by read from feat_lds (bytes 24..39 of row el)
        #pragma unroll
        for (int nj = 0; nj < 4; ++nj) {
            const int el = nj * 16 + t;
            const uint2 byw = *(const uint2*)(fb + (((el << 6) + 24 + jhalf * 8) ^ ((el & 7) << 4)));
            const float f0 = bflo(byw.x), f1 = bfhi(byw.x), f2 = bflo(byw.y), f3 = bfhi(byw.y);
            u32 pks[2];
            #pragma unroll
            for (int d = 0; d < 2; ++d) {
                const f32x4 a = acc[d][nj];
                float p = fmaf(a[0], f0, fmaf(a[1], f1, fmaf(a[2], f2, a[3] * f3)));
                const float m  = p + __shfl_xor(p, 16, 64);   // full dot
                const float mo = __shfl_xor(m, 32, 64);       // partner channel
                pks[d] = pkbf(m, mo);                          // (2mi, 2mi+1) on g==0
            }
            if (g == 0)
                *(uint2*)(msg + (size_t)(s0 + el) * 8 + h * 4) = make_uint2(pks[0], pks[1]);
        }
    }
}

// ---- fused CSR gather + finalize: 8 lanes per node, coalesced uint4 slot reads ----
__global__ __launch_bounds__(256) void gno_gather_out(
    const float* __restrict__ batch, const float* __restrict__ Wlin,
    const u16* __restrict__ msg0, const size_t mstride, const u32* __restrict__ rowptr,
    const u32* __restrict__ cnt, float* __restrict__ out, const int bsel)
{
    const int tid = threadIdx.x;
    const int n = blockIdx.x * 32 + (tid >> 3);
    const int k = tid & 7;
    if (n >= Nn) return;
    const int b = (bsel >= 0) ? bsel : (int)blockIdx.y;
    const u16* msg = msg0 + (size_t)b * mstride;
    const u32 dg = cnt[n];
    const u32 j0 = rowptr[n];
    float acc[8] = {0, 0, 0, 0, 0, 0, 0, 0};
    for (u32 j = j0 + k; j < j0 + dg; j += 8) {
        const uint4 m = *(const uint4*)(msg + (size_t)j * 8);
        acc[0] += bflo(m.x); acc[1] += bfhi(m.x);
        acc[2] += bflo(m.y); acc[3] += bfhi(m.y);
        acc[4] += bflo(m.z); acc[5] += bfhi(m.z);
        acc[6] += bflo(m.w); acc[7] += bfhi(m.w);
    }
    #pragma unroll
    for (int s = 1; s < 8; s <<= 1) {
        #pragma unroll
        for (int c = 0; c < 8; ++c) acc[c] += __shfl_xor(acc[c], s, 64);
    }
    float v = acc[k] * __builtin_amdgcn_rcpf((float)dg + 1.0f);
    const float* br = batch + ((size_t)b * Nn + n) * 8;
    #pragma unroll
    for (int j = 0; j < 8; ++j) v = fmaf(br[j], Wlin[j * FOUT + k], v);
    out[((size_t)b * Nn + n) * 8 + k] = v;   // fully coalesced
}

extern "C" void kernel_launch(void* const* d_in, const int* in_sizes, int n_in,
                              void* d_out, int out_size, void* d_ws, size_t ws_size,
                              hipStream_t stream) {
    const float* batch  = (const float*)d_in[0];
    const float* points = (const float*)d_in[1];
    const int*   neigh  = (const int*)d_in[2];
    const float* W1     = (const float*)d_in[3];
    const float* b1     = (const float*)d_in[4];
    const float* W2     = (const float*)d_in[5];
    const float* b2     = (const float*)d_in[6];
    const float* W3     = (const float*)d_in[7];
    const float* b3     = (const float*)d_in[8];
    const float* Wlin   = (const float*)d_in[9];
    float* out = (float*)d_out;

    unsigned char* ws = (unsigned char*)d_ws;
    u32* cnt    = (u32*)(ws + CNT_OFF);
    u32* rowptr = (u32*)(ws + ROWPTR_OFF);
    u32* bsum   = (u32*)(ws + BSUM_OFF);
    u32* pairs  = (u32*)(ws + PAIRS_OFF);
    u16* rank   = (u16*)(ws + RANK_OFF);     // aliases msg; consumed before msg written
    u16* msg    = (u16*)(ws + MSG_OFF);
    if (ws_size < WS_NEEDED) return;
    const int tier = (ws_size >= WS_4) ? 2 : (ws_size >= WS_CVT) ? 1 : 0;
    u32* pbf = (u32*)(ws + (tier == 2 ? PBF4_OFF : PBF_OFF));
    u16* bbf = (u16*)(ws + (tier == 2 ? BBF4_OFF : BBF_OFF));

    const dim3 b256(256);
    const dim3 gE((En + 255) / 256);
    const dim3 gEdge((En / 64 + 3) / 4);     // 3907
    const dim3 gN((Nn + 255) / 256);         // 196 (<= 256 for scan2)
    const dim3 gGather((Nn + 31) / 32);      // 1563
    const dim3 gCvt((Bn * Nn + 255) / 256);

    hipMemsetAsync(cnt, 0, Nn * sizeof(u32), stream);
    gno_init_weights<<<dim3(41), b256, 0, stream>>>(W1, b1, W2, b2, W3, b3, ws);
    if (tier >= 1)
        gno_cvt<<<gCvt, b256, 0, stream>>>(batch, points, pbf, bbf);
    gno_hist_rank<<<gE, b256, 0, stream>>>(neigh, cnt, rank);
    gno_scan1<<<gN, b256, 0, stream>>>(cnt, rowptr, bsum);
    gno_scan2<<<dim3(1), b256, 0, stream>>>(bsum, (int)gN.x);
    gno_scan3<<<gN, b256, 0, stream>>>(rowptr, bsum);
    gno_slot<<<gE, b256, 0, stream>>>(neigh, rowptr, rank, pairs);

    if (tier == 2) {
        // batch-fused: one edge dispatch (grid.y = batch), 4 msg buffers, one gather
        gno_edge_mfma<1><<<dim3(gEdge.x, Bn), b256, 0, stream>>>(
            batch, points, pairs, ws, -1, msg, MSTRIDE, pbf, bbf);
        gno_gather_out<<<dim3(gGather.x, Bn), b256, 0, stream>>>(
            batch, Wlin, msg, MSTRIDE, rowptr, cnt, out, -1);
    } else {
        for (int b = 0; b < Bn; ++b) {
            if (tier == 1)
                gno_edge_mfma<1><<<gEdge, b256, 0, stream>>>(batch, points, pairs, ws, b,
                                                             msg, 0, pbf, bbf);
            else
                gno_edge_mfma<0><<<gEdge, b256, 0, stream>>>(batch, points, pairs, ws, b,
                                                             msg, 0, pbf, bbf);
            gno_gather_out<<<gGather, b256, 0, stream>>>(batch, Wlin, msg, 0, rowptr,
                                                         cnt, out, b);
        }
    }
}

// Round 20
// 265.286 us; speedup vs baseline: 1.6220x; 1.0599x over previous
//
#include <hip/hip_runtime.h>

#define Bn 4
#define Nn 50000
#define En 1000000
#define FOUT 8

typedef unsigned int u32;
typedef unsigned short u16;
typedef __attribute__((ext_vector_type(8))) short bf16x8;
typedef __attribute__((ext_vector_type(4))) float f32x4;
typedef __attribute__((ext_vector_type(4))) int i32x4;

#define TANH_C 2.8853900817779268f   // 2*log2(e)

// ---- ws layout (bytes) ----
#define BLOB_BYTES 24576
#define W1T_OFF 0       // [64 q][32 k] bf16 (k padded 20->32)
#define W2T_OFF 4096    // [64 q][64 k] bf16
#define W3T_OFF 12288   // [64 c][64 k] bf16
#define B1_OFF 20480
#define B2_OFF 20736
#define B3_OFF 20992
#define BSUM_OFF 21248  // u32[256]
#define B1C_OFF 22528   // f32[64]: TANH_C * b1[PERM(q)]
#define B2C_OFF 22784   // f32[64]: TANH_C * b2[PERM(q)]

#define CNT_OFF    24576
#define ROWPTR_OFF 224576
#define PAIRS_OFF  624768                        // u32[En]: src | dst<<16
#define MSG_OFF    4624768                       // bf16[En*8] (tier<2) / 4 buffers (tier2)
#define RANK_OFF   MSG_OFF                       // u16[En], consumed before msg written
#define WS_NEEDED (MSG_OFF + (size_t)En * FOUT * 2)            // 20,624,768 (proven)
// tier1: cvt buffers after single msg
#define PBF_OFF    20624768
#define BBF_OFF    20824768
#define WS_CVT     (BBF_OFF + (size_t)Bn * Nn * FOUT * 2)      // 24,024,768
// tier2: 4 msg buffers + cvt
#define MSTRIDE    ((size_t)En * FOUT)                          // u16 units per batch
#define PBF4_OFF   (MSG_OFF + (size_t)Bn * En * FOUT * 2)       // 68,624,768
#define BBF4_OFF   (PBF4_OFF + (size_t)Nn * 4)                  // 68,824,768
#define WS_4       (BBF4_OFF + (size_t)Bn * Nn * FOUT * 2)      // 72,024,768

__device__ __forceinline__ float fast_tanh_b(float acc, float cb) {
    float e = __builtin_amdgcn_exp2f(fmaf(acc, TANH_C, cb));
    return 1.0f - 2.0f * __builtin_amdgcn_rcpf(e + 1.0f);
}
__device__ __forceinline__ u32 pkbf(float lo, float hi) {
    u32 r;
    asm("v_cvt_pk_bf16_f32 %0, %1, %2" : "=v"(r) : "v"(lo), "v"(hi));
    return r;
}
__device__ __forceinline__ float bflo(u32 u) { return __builtin_bit_cast(float, u << 16); }
__device__ __forceinline__ float bfhi(u32 u) { return __builtin_bit_cast(float, u & 0xffff0000u); }
__device__ __forceinline__ u16 f2bf(float x) {
    u32 u = __builtin_bit_cast(u32, x);
    return (u16)((u + 0x7fff + ((u >> 16) & 1)) >> 16);
}
// sigma-permutation of MLP hidden channels (HW-verified rounds 4-19)
__device__ __forceinline__ int PERM_Q(int q) {
    int mi = q >> 4, g = (q >> 2) & 3, r = q & 3;
    return ((mi >> 1) << 5) | (g << 3) | ((mi & 1) << 2) | r;
}

__global__ void gno_init_weights(const float* __restrict__ W1, const float* __restrict__ b1,
                                 const float* __restrict__ W2, const float* __restrict__ b2,
                                 const float* __restrict__ W3, const float* __restrict__ b3,
                                 unsigned char* __restrict__ blob)
{
    int idx = blockIdx.x * 256 + threadIdx.x;
    if (idx < 2048) {
        int q = idx >> 5, k = idx & 31;
        float v = (k < 20) ? W1[k * 64 + PERM_Q(q)] : 0.0f;
        *(u16*)(blob + W1T_OFF + q * 64 + 2 * k) = f2bf(v);
    } else if (idx < 6144) {
        int j = idx - 2048, q = j >> 6, k = j & 63;
        *(u16*)(blob + W2T_OFF + q * 128 + 2 * k) = f2bf(W2[k * 64 + PERM_Q(q)]);
    } else if (idx < 10240) {
        int j = idx - 6144, c = j >> 6, k = j & 63;
        *(u16*)(blob + W3T_OFF + c * 128 + 2 * k) = f2bf(W3[k * 64 + c]);
    } else if (idx < 10304) {
        int q = idx - 10240;
        *(float*)(blob + B1_OFF + q * 4) = b1[PERM_Q(q)];
        *(float*)(blob + B1C_OFF + q * 4) = TANH_C * b1[PERM_Q(q)];
    } else if (idx < 10368) {
        int q = idx - 10304;
        *(float*)(blob + B2_OFF + q * 4) = b2[PERM_Q(q)];
        *(float*)(blob + B2C_OFF + q * 4) = TANH_C * b2[PERM_Q(q)];
    } else if (idx < 10432) { int c = idx - 10368; *(float*)(blob + B3_OFF + c * 4) = b3[c]; }
}

// ---- bf16 pre-conversion ----
__global__ void gno_cvt(const float* __restrict__ batch, const float* __restrict__ points,
                        u32* __restrict__ pbf, u16* __restrict__ bbf)
{
    const int t = blockIdx.x * 256 + threadIdx.x;
    if (t < Bn * Nn) {
        const float4* bp = (const float4*)(batch + (size_t)t * 8);
        const float4 a = bp[0], c = bp[1];
        *(uint4*)(bbf + (size_t)t * 8) =
            make_uint4(pkbf(a.x, a.y), pkbf(a.z, a.w), pkbf(c.x, c.y), pkbf(c.z, c.w));
    }
    if (t < Nn) {
        const float2 pp = *(const float2*)(points + 2 * (size_t)t);
        pbf[t] = pkbf(pp.x, pp.y);
    }
}

// ---- CSR build: rank-fused (proven round 17) ----
__global__ void gno_hist_rank(const int* __restrict__ neigh, u32* __restrict__ cnt,
                              u16* __restrict__ rank) {
    const int e = blockIdx.x * 256 + threadIdx.x;
    if (e < En) rank[e] = (u16)atomicAdd(&cnt[neigh[e]], 1u);
}
__global__ __launch_bounds__(256) void gno_scan1(const u32* __restrict__ cnt,
                                                 u32* __restrict__ rowptr,
                                                 u32* __restrict__ bsum)
{
    __shared__ u32 wtot[4];
    const int tid = threadIdx.x, lane = tid & 63, w = tid >> 6;
    const int n = blockIdx.x * 256 + tid;
    const u32 c = (n < Nn) ? cnt[n] : 0u;
    u32 inc = c;
    #pragma unroll
    for (int off = 1; off < 64; off <<= 1) {
        u32 x = __shfl_up(inc, off, 64);
        if (lane >= off) inc += x;
    }
    if (lane == 63) wtot[w] = inc;
    __syncthreads();
    u32 woff = 0;
    for (int i = 0; i < w; ++i) woff += wtot[i];
    if (n < Nn) rowptr[n] = woff + inc - c;
    if (tid == 255) bsum[blockIdx.x] = woff + inc;
}
__global__ __launch_bounds__(256) void gno_scan2(u32* __restrict__ bsum, const int nb)
{
    __shared__ u32 wtot[4];
    const int tid = threadIdx.x, lane = tid & 63, w = tid >> 6;
    const u32 c = (tid < nb) ? bsum[tid] : 0u;
    u32 inc = c;
    #pragma unroll
    for (int off = 1; off < 64; off <<= 1) {
        u32 x = __shfl_up(inc, off, 64);
        if (lane >= off) inc += x;
    }
    if (lane == 63) wtot[w] = inc;
    __syncthreads();
    u32 woff = 0;
    for (int i = 0; i < w; ++i) woff += wtot[i];
    if (tid < nb) bsum[tid] = woff + inc - c;
}
__global__ __launch_bounds__(256) void gno_scan3(u32* __restrict__ rowptr,
                                                 const u32* __restrict__ bsum)
{
    const int n = blockIdx.x * 256 + threadIdx.x;
    if (n < Nn) rowptr[n] += bsum[blockIdx.x];
    if (n == 0) rowptr[Nn] = En;
}
__global__ void gno_slot(const int* __restrict__ neigh, const u32* __restrict__ rowptr,
                         const u16* __restrict__ rank, u32* __restrict__ pairs) {
    const int e = blockIdx.x * 256 + threadIdx.x;
    if (e < En) {
        const int dn = neigh[e];
        const int sn = neigh[En + e];
        const u32 s = rowptr[dn] + rank[e];
        pairs[s] = (u32)sn | ((u32)dn << 16);
    }
}

// ---- edge MLP over CSR slot order: 4 waves x 64 slots per block ----
// PERMANENT (256,4): spill ledger r8/r10/r12/r14. Round 20: epilogue fixes --
// (1) one uint4 msg store/slot (was 2x8B split across h: ~2x write amplification
// with 4 concurrent batch streams, r19 WRITE=174MB); (2) by-read hoisted out of
// the h loop (halves the conflicted LDS reads, r19 conflicts 1.5M).
template<int CVT>
__global__ __launch_bounds__(256, 4) void gno_edge_mfma(
    const float* __restrict__ batch, const float* __restrict__ points,
    const u32* __restrict__ pairs, const unsigned char* __restrict__ wblob,
    const int bsel, u16* __restrict__ msg0, const size_t mstride,
    const u32* __restrict__ pbf, const u16* __restrict__ bbf)
{
    __shared__ __align__(128) unsigned char feat_lds[4 * 64 * 64];  // [w][e][32 bf16]

    const int tid = threadIdx.x;
    const int lane = tid & 63;
    const int w = tid >> 6;
    const int s0 = (blockIdx.x * 4 + w) * 64;
    if (s0 >= En) return;                  // wave-uniform tail guard; no barriers
    const int t = lane & 15;
    const int g = lane >> 4;
    const int b = (bsel >= 0) ? bsel : (int)blockIdx.y;
    u16* __restrict__ msg = msg0 + (size_t)b * mstride;
    unsigned char* fb = feat_lds + w * 4096;

    // stage feat: all 64 lanes, one slot each (wave-private region, in-wave ordering)
    {
        const u32 p = pairs[s0 + lane];
        const int sn = (int)(p & 0xffffu);
        const int dn = (int)(p >> 16);
        const int base = lane << 6;
        const int sw = (lane & 7) << 4;
        if constexpr (CVT) {
            const u32 pspk = pbf[sn];
            const u32 pdpk = pbf[dn];
            const uint4 bx = *(const uint4*)(bbf + ((size_t)b * Nn + sn) * 8);
            const uint4 by = *(const uint4*)(bbf + ((size_t)b * Nn + dn) * 8);
            *(uint4*)(fb + ((base + 0)  ^ sw)) = make_uint4(pspk, pdpk, bx.x, bx.y);
            *(uint4*)(fb + ((base + 16) ^ sw)) = make_uint4(bx.z, bx.w, by.x, by.y);
            *(uint4*)(fb + ((base + 32) ^ sw)) = make_uint4(by.z, by.w, 0u, 0u);
            *(uint4*)(fb + ((base + 48) ^ sw)) = make_uint4(0u, 0u, 0u, 0u);
        } else {
            const float2 ps = *(const float2*)(points + 2 * (size_t)sn);
            const float2 pd = *(const float2*)(points + 2 * (size_t)dn);
            const float4* bxp = (const float4*)(batch + ((size_t)b * Nn + sn) * 8);
            const float4 bx0 = bxp[0], bx1 = bxp[1];
            const float4* byp = (const float4*)(batch + ((size_t)b * Nn + dn) * 8);
            const float4 by0 = byp[0], by1 = byp[1];
            *(uint4*)(fb + ((base + 0)  ^ sw)) = make_uint4(pkbf(ps.x, ps.y), pkbf(pd.x, pd.y),
                                                            pkbf(bx0.x, bx0.y), pkbf(bx0.z, bx0.w));
            *(uint4*)(fb + ((base + 16) ^ sw)) = make_uint4(pkbf(bx1.x, bx1.y), pkbf(bx1.z, bx1.w),
                                                            pkbf(by0.x, by0.y), pkbf(by0.z, by0.w));
            *(uint4*)(fb + ((base + 32) ^ sw)) = make_uint4(pkbf(by1.x, by1.y), pkbf(by1.z, by1.w), 0u, 0u);
            *(uint4*)(fb + ((base + 48) ^ sw)) = make_uint4(0u, 0u, 0u, 0u);
        }
    }

    u32 pk1[4][4][2];   // L1 outputs, packed bf16 (sigma: lane-held == lane-needed)

    // ----- L1 (K=32), M in two halves; acc from 0, bias in tanh exponent -----
    {
        bf16x8 bfr[4];
        #pragma unroll
        for (int nj = 0; nj < 4; ++nj) {
            const int row = nj * 16 + t;
            bfr[nj] = *(const bf16x8*)(feat_lds + w * 4096 + ((row * 64 + (g << 4)) ^ ((row & 7) << 4)));
        }
        #pragma unroll
        for (int h = 0; h < 2; ++h) {
            f32x4 acc[2][4] = {};
            bf16x8 afr[2];
            f32x4 cbv[2];
            #pragma unroll
            for (int d = 0; d < 2; ++d) {
                const int mi = 2 * h + d;
                cbv[d] = *(const f32x4*)(wblob + B1C_OFF + (mi * 16 + g * 4) * 4);
                afr[d] = *(const bf16x8*)(wblob + W1T_OFF + (mi * 16 + t) * 64 + (g << 4));
            }
            #pragma unroll
            for (int d = 0; d < 2; ++d)
                #pragma unroll
                for (int nj = 0; nj < 4; ++nj)
                    acc[d][nj] = __builtin_amdgcn_mfma_f32_16x16x32_bf16(afr[d], bfr[nj], acc[d][nj], 0, 0, 0);
            #pragma unroll
            for (int d = 0; d < 2; ++d)
                #pragma unroll
                for (int nj = 0; nj < 4; ++nj) {
                    pk1[2 * h + d][nj][0] = pkbf(fast_tanh_b(acc[d][nj][0], cbv[d][0]),
                                                 fast_tanh_b(acc[d][nj][1], cbv[d][1]));
                    pk1[2 * h + d][nj][1] = pkbf(fast_tanh_b(acc[d][nj][2], cbv[d][2]),
                                                 fast_tanh_b(acc[d][nj][3], cbv[d][3]));
                }
        }
    }

    // ----- L2 (K=64), M in two halves; B-frags from pk1 registers -----
    u32 pk2[4][4][2];
    #pragma unroll
    for (int h = 0; h < 2; ++h) {
        f32x4 acc[2][4] = {};
        f32x4 cbv[2];
        #pragma unroll
        for (int d = 0; d < 2; ++d)
            cbv[d] = *(const f32x4*)(wblob + B2C_OFF + ((2 * h + d) * 16 + g * 4) * 4);
        #pragma unroll
        for (int kt = 0; kt < 2; ++kt) {
            bf16x8 afr[2];
            #pragma unroll
            for (int d = 0; d < 2; ++d)
                afr[d] = *(const bf16x8*)(wblob + W2T_OFF + ((2 * h + d) * 16 + t) * 128 + kt * 64 + (g << 4));
            #pragma unroll
            for (int nj = 0; nj < 4; ++nj) {
                const i32x4 bi = { (int)pk1[2 * kt][nj][0], (int)pk1[2 * kt][nj][1],
                                   (int)pk1[2 * kt + 1][nj][0], (int)pk1[2 * kt + 1][nj][1] };
                const bf16x8 bf = __builtin_bit_cast(bf16x8, bi);
                #pragma unroll
                for (int d = 0; d < 2; ++d)
                    acc[d][nj] = __builtin_amdgcn_mfma_f32_16x16x32_bf16(afr[d], bf, acc[d][nj], 0, 0, 0);
            }
        }
        #pragma unroll
        for (int d = 0; d < 2; ++d)
            #pragma unroll
            for (int nj = 0; nj < 4; ++nj) {
                pk2[2 * h + d][nj][0] = pkbf(fast_tanh_b(acc[d][nj][0], cbv[d][0]),
                                             fast_tanh_b(acc[d][nj][1], cbv[d][1]));
                pk2[2 * h + d][nj][1] = pkbf(fast_tanh_b(acc[d][nj][2], cbv[d][2]),
                                             fast_tanh_b(acc[d][nj][3], cbv[d][3]));
            }
    }

    // ----- L3 (K=64) + fused epilogue, M in two halves -----
    // byw hoisted (read once per nj); h=0 results buffered in mbuf, single
    // uint4 store per slot at h=1 (full-line write-combining).
    const int jhalf = g & 1;
    uint2 byw[4];
    #pragma unroll
    for (int nj = 0; nj < 4; ++nj) {
        const int el = nj * 16 + t;
        byw[nj] = *(const uint2*)(fb + (((el << 6) + 24 + jhalf * 8) ^ ((el & 7) << 4)));
    }
    u32 mbuf[4][2];
    #pragma unroll
    for (int h = 0; h < 2; ++h) {
        f32x4 acc[2][4];
        #pragma unroll
        for (int d = 0; d < 2; ++d) {
            const int mi = 2 * h + d;
            const f32x4 bv = *(const f32x4*)(wblob + B3_OFF + (mi * 16 + g * 4) * 4);
            #pragma unroll
            for (int nj = 0; nj < 4; ++nj) acc[d][nj] = bv;
        }
        #pragma unroll
        for (int kt = 0; kt < 2; ++kt) {
            bf16x8 afr[2];
            #pragma unroll
            for (int d = 0; d < 2; ++d)
                afr[d] = *(const bf16x8*)(wblob + W3T_OFF + ((2 * h + d) * 16 + t) * 128 + kt * 64 + (g << 4));
            #pragma unroll
            for (int nj = 0; nj < 4; ++nj) {
                const i32x4 bi = { (int)pk2[2 * kt][nj][0], (int)pk2[2 * kt][nj][1],
                                   (int)pk2[2 * kt + 1][nj][0], (int)pk2[2 * kt + 1][nj][1] };
                const bf16x8 bf = __builtin_bit_cast(bf16x8, bi);
                #pragma unroll
                for (int d = 0; d < 2; ++d)
                    acc[d][nj] = __builtin_amdgcn_mfma_f32_16x16x32_bf16(afr[d], bf, acc[d][nj], 0, 0, 0);
            }
        }
        #pragma unroll
        for (int nj = 0; nj < 4; ++nj) {
            const float f0 = bflo(byw[nj].x), f1 = bfhi(byw[nj].x);
            const float f2 = bflo(byw[nj].y), f3 = bfhi(byw[nj].y);
            u32 pks[2];
            #pragma unroll
            for (int d = 0; d < 2; ++d) {
                const f32x4 a = acc[d][nj];
                float p = fmaf(a[0], f0, fmaf(a[1], f1, fmaf(a[2], f2, a[3] * f3)));
                const float m  = p + __shfl_xor(p, 16, 64);   // full dot
                const float mo = __shfl_xor(m, 32, 64);       // partner channel
                pks[d] = pkbf(m, mo);                          // (2mi, 2mi+1) on g==0
            }
            if (h == 0) {
                mbuf[nj][0] = pks[0]; mbuf[nj][1] = pks[1];
            } else if (g == 0) {
                const int el = nj * 16 + t;
                *(uint4*)(msg + (size_t)(s0 + el) * 8) =
                    make_uint4(mbuf[nj][0], mbuf[nj][1], pks[0], pks[1]);
            }
        }
    }
}

// ---- fused CSR gather + finalize: 8 lanes per node, coalesced uint4 slot reads ----
__global__ __launch_bounds__(256) void gno_gather_out(
    const float* __restrict__ batch, const float* __restrict__ Wlin,
    const u16* __restrict__ msg0, const size_t mstride, const u32* __restrict__ rowptr,
    const u32* __restrict__ cnt, float* __restrict__ out, const int bsel)
{
    const int tid = threadIdx.x;
    const int n = blockIdx.x * 32 + (tid >> 3);
    const int k = tid & 7;
    if (n >= Nn) return;
    const int b = (bsel >= 0) ? bsel : (int)blockIdx.y;
    const u16* msg = msg0 + (size_t)b * mstride;
    const u32 dg = cnt[n];
    const u32 j0 = rowptr[n];
    float acc[8] = {0, 0, 0, 0, 0, 0, 0, 0};
    for (u32 j = j0 + k; j < j0 + dg; j += 8) {
        const uint4 m = *(const uint4*)(msg + (size_t)j * 8);
        acc[0] += bflo(m.x); acc[1] += bfhi(m.x);
        acc[2] += bflo(m.y); acc[3] += bfhi(m.y);
        acc[4] += bflo(m.z); acc[5] += bfhi(m.z);
        acc[6] += bflo(m.w); acc[7] += bfhi(m.w);
    }
    #pragma unroll
    for (int s = 1; s < 8; s <<= 1) {
        #pragma unroll
        for (int c = 0; c < 8; ++c) acc[c] += __shfl_xor(acc[c], s, 64);
    }
    float v = acc[k] * __builtin_amdgcn_rcpf((float)dg + 1.0f);
    const float* br = batch + ((size_t)b * Nn + n) * 8;
    #pragma unroll
    for (int j = 0; j < 8; ++j) v = fmaf(br[j], Wlin[j * FOUT + k], v);
    out[((size_t)b * Nn + n) * 8 + k] = v;   // fully coalesced
}

extern "C" void kernel_launch(void* const* d_in, const int* in_sizes, int n_in,
                              void* d_out, int out_size, void* d_ws, size_t ws_size,
                              hipStream_t stream) {
    const float* batch  = (const float*)d_in[0];
    const float* points = (const float*)d_in[1];
    const int*   neigh  = (const int*)d_in[2];
    const float* W1     = (const float*)d_in[3];
    const float* b1     = (const float*)d_in[4];
    const float* W2     = (const float*)d_in[5];
    const float* b2     = (const float*)d_in[6];
    const float* W3     = (const float*)d_in[7];
    const float* b3     = (const float*)d_in[8];
    const float* Wlin   = (const float*)d_in[9];
    float* out = (float*)d_out;

    unsigned char* ws = (unsigned char*)d_ws;
    u32* cnt    = (u32*)(ws + CNT_OFF);
    u32* rowptr = (u32*)(ws + ROWPTR_OFF);
    u32* bsum   = (u32*)(ws + BSUM_OFF);
    u32* pairs  = (u32*)(ws + PAIRS_OFF);
    u16* rank   = (u16*)(ws + RANK_OFF);     // aliases msg; consumed before msg written
    u16* msg    = (u16*)(ws + MSG_OFF);
    if (ws_size < WS_NEEDED) return;
    const int tier = (ws_size >= WS_4) ? 2 : (ws_size >= WS_CVT) ? 1 : 0;
    u32* pbf = (u32*)(ws + (tier == 2 ? PBF4_OFF : PBF_OFF));
    u16* bbf = (u16*)(ws + (tier == 2 ? BBF4_OFF : BBF_OFF));

    const dim3 b256(256);
    const dim3 gE((En + 255) / 256);
    const dim3 gEdge((En / 64 + 3) / 4);     // 3907
    const dim3 gN((Nn + 255) / 256);         // 196 (<= 256 for scan2)
    const dim3 gGather((Nn + 31) / 32);      // 1563
    const dim3 gCvt((Bn * Nn + 255) / 256);

    hipMemsetAsync(cnt, 0, Nn * sizeof(u32), stream);
    gno_init_weights<<<dim3(41), b256, 0, stream>>>(W1, b1, W2, b2, W3, b3, ws);
    if (tier >= 1)
        gno_cvt<<<gCvt, b256, 0, stream>>>(batch, points, pbf, bbf);
    gno_hist_rank<<<gE, b256, 0, stream>>>(neigh, cnt, rank);
    gno_scan1<<<gN, b256, 0, stream>>>(cnt, rowptr, bsum);
    gno_scan2<<<dim3(1), b256, 0, stream>>>(bsum, (int)gN.x);
    gno_scan3<<<gN, b256, 0, stream>>>(rowptr, bsum);
    gno_slot<<<gE, b256, 0, stream>>>(neigh, rowptr, rank, pairs);

    if (tier == 2) {
        gno_edge_mfma<1><<<dim3(gEdge.x, Bn), b256, 0, stream>>>(
            batch, points, pairs, ws, -1, msg, MSTRIDE, pbf, bbf);
        gno_gather_out<<<dim3(gGather.x, Bn), b256, 0, stream>>>(
            batch, Wlin, msg, MSTRIDE, rowptr, cnt, out, -1);
    } else {
        for (int b = 0; b < Bn; ++b) {
            if (tier == 1)
                gno_edge_mfma<1><<<gEdge, b256, 0, stream>>>(batch, points, pairs, ws, b,
                                                             msg, 0, pbf, bbf);
            else
                gno_edge_mfma<0><<<gEdge, b256, 0, stream>>>(batch, points, pairs, ws, b,
                                                             msg, 0, pbf, bbf);
            gno_gather_out<<<gGather, b256, 0, stream>>>(batch, Wlin, msg, 0, rowptr,
                                                         cnt, out, b);
        }
    }
}

// Round 22
// 263.278 us; speedup vs baseline: 1.6344x; 1.0076x over previous
//
#include <hip/hip_runtime.h>

#define Bn 4
#define Nn 50000
#define En 1000000
#define FOUT 8

typedef unsigned int u32;
typedef unsigned short u16;
typedef __attribute__((ext_vector_type(8))) short bf16x8;
typedef __attribute__((ext_vector_type(4))) float f32x4;
typedef __attribute__((ext_vector_type(4))) int i32x4;

#define TANH_C 2.8853900817779268f   // 2*log2(e)

// ---- ws layout (bytes) ----
#define BLOB_BYTES 24576
#define W1T_OFF 0       // [64 q][32 k] bf16 (k padded 20->32)
#define W2T_OFF 4096    // [64 q][64 k] bf16
#define W3T_OFF 12288   // [64 c][64 k] bf16
#define B1_OFF 20480
#define B2_OFF 20736
#define B3_OFF 20992
#define BSUM_OFF 21248  // u32[256]
#define B1C_OFF 22528   // f32[64]: TANH_C * b1[PERM(q)]
#define B2C_OFF 22784   // f32[64]: TANH_C * b2[PERM(q)]

#define CNT_OFF    24576
#define ROWPTR_OFF 224576
#define PAIRS_OFF  624768                        // u32[En]: src | dst<<16
#define MSG_OFF    4624768                       // bf16[En*8] (tier<2) / 4 buffers (tier2)
#define RANK_OFF   MSG_OFF                       // u16[En], consumed before msg written
#define WS_NEEDED (MSG_OFF + (size_t)En * FOUT * 2)            // 20,624,768 (proven)
#define PBF_OFF    20624768
#define BBF_OFF    20824768
#define WS_CVT     (BBF_OFF + (size_t)Bn * Nn * FOUT * 2)      // 24,024,768
#define MSTRIDE    ((size_t)En * FOUT)                          // u16 units per batch
#define PBF4_OFF   (MSG_OFF + (size_t)Bn * En * FOUT * 2)       // 68,624,768
#define BBF4_OFF   (PBF4_OFF + (size_t)Nn * 4)                  // 68,824,768
#define WS_4       (BBF4_OFF + (size_t)Bn * Nn * FOUT * 2)      // 72,024,768

// tanh with bias folded: tanh(acc + b) = 1 - 2*rcp(exp2(acc*C + C*b) + 1)
// NOTE (r21 ledger): the "r-folding" variant (emit rcp term, fold 1-2r into
// -2*W / rowsum biases) produced NaN on HW despite passing symbolic checks.
// REFUTED-IN-PRACTICE; do not re-attempt without intermediate visibility.
__device__ __forceinline__ float fast_tanh_b(float acc, float cb) {
    float e = __builtin_amdgcn_exp2f(fmaf(acc, TANH_C, cb));
    return 1.0f - 2.0f * __builtin_amdgcn_rcpf(e + 1.0f);
}
__device__ __forceinline__ u32 pkbf(float lo, float hi) {
    u32 r;
    asm("v_cvt_pk_bf16_f32 %0, %1, %2" : "=v"(r) : "v"(lo), "v"(hi));
    return r;
}
__device__ __forceinline__ float bflo(u32 u) { return __builtin_bit_cast(float, u << 16); }
__device__ __forceinline__ float bfhi(u32 u) { return __builtin_bit_cast(float, u & 0xffff0000u); }
__device__ __forceinline__ u16 f2bf(float x) {
    u32 u = __builtin_bit_cast(u32, x);
    return (u16)((u + 0x7fff + ((u >> 16) & 1)) >> 16);
}
// sigma-permutation of MLP hidden channels (HW-verified rounds 4-20)
__device__ __forceinline__ int PERM_Q(int q) {
    int mi = q >> 4, g = (q >> 2) & 3, r = q & 3;
    return ((mi >> 1) << 5) | (g << 3) | ((mi & 1) << 2) | r;
}

__global__ void gno_init_weights(const float* __restrict__ W1, const float* __restrict__ b1,
                                 const float* __restrict__ W2, const float* __restrict__ b2,
                                 const float* __restrict__ W3, const float* __restrict__ b3,
                                 unsigned char* __restrict__ blob)
{
    int idx = blockIdx.x * 256 + threadIdx.x;
    if (idx < 2048) {
        int q = idx >> 5, k = idx & 31;
        float v = (k < 20) ? W1[k * 64 + PERM_Q(q)] : 0.0f;
        *(u16*)(blob + W1T_OFF + q * 64 + 2 * k) = f2bf(v);
    } else if (idx < 6144) {
        int j = idx - 2048, q = j >> 6, k = j & 63;
        *(u16*)(blob + W2T_OFF + q * 128 + 2 * k) = f2bf(W2[k * 64 + PERM_Q(q)]);
    } else if (idx < 10240) {
        int j = idx - 6144, c = j >> 6, k = j & 63;
        *(u16*)(blob + W3T_OFF + c * 128 + 2 * k) = f2bf(W3[k * 64 + c]);
    } else if (idx < 10304) {
        int q = idx - 10240;
        *(float*)(blob + B1_OFF + q * 4) = b1[PERM_Q(q)];
        *(float*)(blob + B1C_OFF + q * 4) = TANH_C * b1[PERM_Q(q)];
    } else if (idx < 10368) {
        int q = idx - 10304;
        *(float*)(blob + B2_OFF + q * 4) = b2[PERM_Q(q)];
        *(float*)(blob + B2C_OFF + q * 4) = TANH_C * b2[PERM_Q(q)];
    } else if (idx < 10432) { int c = idx - 10368; *(float*)(blob + B3_OFF + c * 4) = b3[c]; }
}

// ---- bf16 pre-conversion ----
__global__ void gno_cvt(const float* __restrict__ batch, const float* __restrict__ points,
                        u32* __restrict__ pbf, u16* __restrict__ bbf)
{
    const int t = blockIdx.x * 256 + threadIdx.x;
    if (t < Bn * Nn) {
        const float4* bp = (const float4*)(batch + (size_t)t * 8);
        const float4 a = bp[0], c = bp[1];
        *(uint4*)(bbf + (size_t)t * 8) =
            make_uint4(pkbf(a.x, a.y), pkbf(a.z, a.w), pkbf(c.x, c.y), pkbf(c.z, c.w));
    }
    if (t < Nn) {
        const float2 pp = *(const float2*)(points + 2 * (size_t)t);
        pbf[t] = pkbf(pp.x, pp.y);
    }
}

// ---- CSR build: rank-fused (proven round 17) ----
__global__ void gno_hist_rank(const int* __restrict__ neigh, u32* __restrict__ cnt,
                              u16* __restrict__ rank) {
    const int e = blockIdx.x * 256 + threadIdx.x;
    if (e < En) rank[e] = (u16)atomicAdd(&cnt[neigh[e]], 1u);
}
__global__ __launch_bounds__(256) void gno_scan1(const u32* __restrict__ cnt,
                                                 u32* __restrict__ rowptr,
                                                 u32* __restrict__ bsum)
{
    __shared__ u32 wtot[4];
    const int tid = threadIdx.x, lane = tid & 63, w = tid >> 6;
    const int n = blockIdx.x * 256 + tid;
    const u32 c = (n < Nn) ? cnt[n] : 0u;
    u32 inc = c;
    #pragma unroll
    for (int off = 1; off < 64; off <<= 1) {
        u32 x = __shfl_up(inc, off, 64);
        if (lane >= off) inc += x;
    }
    if (lane == 63) wtot[w] = inc;
    __syncthreads();
    u32 woff = 0;
    for (int i = 0; i < w; ++i) woff += wtot[i];
    if (n < Nn) rowptr[n] = woff + inc - c;
    if (tid == 255) bsum[blockIdx.x] = woff + inc;
}
__global__ __launch_bounds__(256) void gno_scan2(u32* __restrict__ bsum, const int nb)
{
    __shared__ u32 wtot[4];
    const int tid = threadIdx.x, lane = tid & 63, w = tid >> 6;
    const u32 c = (tid < nb) ? bsum[tid] : 0u;
    u32 inc = c;
    #pragma unroll
    for (int off = 1; off < 64; off <<= 1) {
        u32 x = __shfl_up(inc, off, 64);
        if (lane >= off) inc += x;
    }
    if (lane == 63) wtot[w] = inc;
    __syncthreads();
    u32 woff = 0;
    for (int i = 0; i < w; ++i) woff += wtot[i];
    if (tid < nb) bsum[tid] = woff + inc - c;
}
__global__ __launch_bounds__(256) void gno_scan3(u32* __restrict__ rowptr,
                                                 const u32* __restrict__ bsum)
{
    const int n = blockIdx.x * 256 + threadIdx.x;
    if (n < Nn) rowptr[n] += bsum[blockIdx.x];
    if (n == 0) rowptr[Nn] = En;
}
__global__ void gno_slot(const int* __restrict__ neigh, const u32* __restrict__ rowptr,
                         const u16* __restrict__ rank, u32* __restrict__ pairs) {
    const int e = blockIdx.x * 256 + threadIdx.x;
    if (e < En) {
        const int dn = neigh[e];
        const int sn = neigh[En + e];
        const u32 s = rowptr[dn] + rank[e];
        pairs[s] = (u32)sn | ((u32)dn << 16);
    }
}

// ---- edge MLP over CSR slot order: 4 waves x 64 slots per block ----
// PERMANENT (256,4): spill ledger r8/r10/r12/r14. r20: uint4 msg store (no write
// amplification) + by-read hoisted out of the h loop. r21 r-folding: REFUTED (NaN).
template<int CVT>
__global__ __launch_bounds__(256, 4) void gno_edge_mfma(
    const float* __restrict__ batch, const float* __restrict__ points,
    const u32* __restrict__ pairs, const unsigned char* __restrict__ wblob,
    const int bsel, u16* __restrict__ msg0, const size_t mstride,
    const u32* __restrict__ pbf, const u16* __restrict__ bbf)
{
    __shared__ __align__(128) unsigned char feat_lds[4 * 64 * 64];  // [w][e][32 bf16]

    const int tid = threadIdx.x;
    const int lane = tid & 63;
    const int w = tid >> 6;
    const int s0 = (blockIdx.x * 4 + w) * 64;
    if (s0 >= En) return;                  // wave-uniform tail guard; no barriers
    const int t = lane & 15;
    const int g = lane >> 4;
    const int b = (bsel >= 0) ? bsel : (int)blockIdx.y;
    u16* __restrict__ msg = msg0 + (size_t)b * mstride;
    unsigned char* fb = feat_lds + w * 4096;

    // stage feat: all 64 lanes, one slot each (wave-private region, in-wave ordering)
    {
        const u32 p = pairs[s0 + lane];
        const int sn = (int)(p & 0xffffu);
        const int dn = (int)(p >> 16);
        const int base = lane << 6;
        const int sw = (lane & 7) << 4;
        if constexpr (CVT) {
            const u32 pspk = pbf[sn];
            const u32 pdpk = pbf[dn];
            const uint4 bx = *(const uint4*)(bbf + ((size_t)b * Nn + sn) * 8);
            const uint4 by = *(const uint4*)(bbf + ((size_t)b * Nn + dn) * 8);
            *(uint4*)(fb + ((base + 0)  ^ sw)) = make_uint4(pspk, pdpk, bx.x, bx.y);
            *(uint4*)(fb + ((base + 16) ^ sw)) = make_uint4(bx.z, bx.w, by.x, by.y);
            *(uint4*)(fb + ((base + 32) ^ sw)) = make_uint4(by.z, by.w, 0u, 0u);
            *(uint4*)(fb + ((base + 48) ^ sw)) = make_uint4(0u, 0u, 0u, 0u);
        } else {
            const float2 ps = *(const float2*)(points + 2 * (size_t)sn);
            const float2 pd = *(const float2*)(points + 2 * (size_t)dn);
            const float4* bxp = (const float4*)(batch + ((size_t)b * Nn + sn) * 8);
            const float4 bx0 = bxp[0], bx1 = bxp[1];
            const float4* byp = (const float4*)(batch + ((size_t)b * Nn + dn) * 8);
            const float4 by0 = byp[0], by1 = byp[1];
            *(uint4*)(fb + ((base + 0)  ^ sw)) = make_uint4(pkbf(ps.x, ps.y), pkbf(pd.x, pd.y),
                                                            pkbf(bx0.x, bx0.y), pkbf(bx0.z, bx0.w));
            *(uint4*)(fb + ((base + 16) ^ sw)) = make_uint4(pkbf(bx1.x, bx1.y), pkbf(bx1.z, bx1.w),
                                                            pkbf(by0.x, by0.y), pkbf(by0.z, by0.w));
            *(uint4*)(fb + ((base + 32) ^ sw)) = make_uint4(pkbf(by1.x, by1.y), pkbf(by1.z, by1.w), 0u, 0u);
            *(uint4*)(fb + ((base + 48) ^ sw)) = make_uint4(0u, 0u, 0u, 0u);
        }
    }

    u32 pk1[4][4][2];   // L1 outputs, packed bf16 (sigma: lane-held == lane-needed)

    // ----- L1 (K=32), M in two halves; acc from 0, bias in tanh exponent -----
    {
        bf16x8 bfr[4];
        #pragma unroll
        for (int nj = 0; nj < 4; ++nj) {
            const int row = nj * 16 + t;
            bfr[nj] = *(const bf16x8*)(feat_lds + w * 4096 + ((row * 64 + (g << 4)) ^ ((row & 7) << 4)));
        }
        #pragma unroll
        for (int h = 0; h < 2; ++h) {
            f32x4 acc[2][4] = {};
            bf16x8 afr[2];
            f32x4 cbv[2];
            #pragma unroll
            for (int d = 0; d < 2; ++d) {
                const int mi = 2 * h + d;
                cbv[d] = *(const f32x4*)(wblob + B1C_OFF + (mi * 16 + g * 4) * 4);
                afr[d] = *(const bf16x8*)(wblob + W1T_OFF + (mi * 16 + t) * 64 + (g << 4));
            }
            #pragma unroll
            for (int d = 0; d < 2; ++d)
                #pragma unroll
                for (int nj = 0; nj < 4; ++nj)
                    acc[d][nj] = __builtin_amdgcn_mfma_f32_16x16x32_bf16(afr[d], bfr[nj], acc[d][nj], 0, 0, 0);
            #pragma unroll
            for (int d = 0; d < 2; ++d)
                #pragma unroll
                for (int nj = 0; nj < 4; ++nj) {
                    pk1[2 * h + d][nj][0] = pkbf(fast_tanh_b(acc[d][nj][0], cbv[d][0]),
                                                 fast_tanh_b(acc[d][nj][1], cbv[d][1]));
                    pk1[2 * h + d][nj][1] = pkbf(fast_tanh_b(acc[d][nj][2], cbv[d][2]),
                                                 fast_tanh_b(acc[d][nj][3], cbv[d][3]));
                }
        }
    }

    // ----- L2 (K=64), M in two halves; B-frags from pk1 registers -----
    u32 pk2[4][4][2];
    #pragma unroll
    for (int h = 0; h < 2; ++h) {
        f32x4 acc[2][4] = {};
        f32x4 cbv[2];
        #pragma unroll
        for (int d = 0; d < 2; ++d)
            cbv[d] = *(const f32x4*)(wblob + B2C_OFF + ((2 * h + d) * 16 + g * 4) * 4);
        #pragma unroll
        for (int kt = 0; kt < 2; ++kt) {
            bf16x8 afr[2];
            #pragma unroll
            for (int d = 0; d < 2; ++d)
                afr[d] = *(const bf16x8*)(wblob + W2T_OFF + ((2 * h + d) * 16 + t) * 128 + kt * 64 + (g << 4));
            #pragma unroll
            for (int nj = 0; nj < 4; ++nj) {
                const i32x4 bi = { (int)pk1[2 * kt][nj][0], (int)pk1[2 * kt][nj][1],
                                   (int)pk1[2 * kt + 1][nj][0], (int)pk1[2 * kt + 1][nj][1] };
                const bf16x8 bf = __builtin_bit_cast(bf16x8, bi);
                #pragma unroll
                for (int d = 0; d < 2; ++d)
                    acc[d][nj] = __builtin_amdgcn_mfma_f32_16x16x32_bf16(afr[d], bf, acc[d][nj], 0, 0, 0);
            }
        }
        #pragma unroll
        for (int d = 0; d < 2; ++d)
            #pragma unroll
            for (int nj = 0; nj < 4; ++nj) {
                pk2[2 * h + d][nj][0] = pkbf(fast_tanh_b(acc[d][nj][0], cbv[d][0]),
                                             fast_tanh_b(acc[d][nj][1], cbv[d][1]));
                pk2[2 * h + d][nj][1] = pkbf(fast_tanh_b(acc[d][nj][2], cbv[d][2]),
                                             fast_tanh_b(acc[d][nj][3], cbv[d][3]));
            }
    }

    // ----- L3 (K=64) + fused epilogue, M in two halves -----
    const int jhalf = g & 1;
    uint2 byw[4];
    #pragma unroll
    for (int nj = 0; nj < 4; ++nj) {
        const int el = nj * 16 + t;
        byw[nj] = *(const uint2*)(fb + (((el << 6) + 24 + jhalf * 8) ^ ((el & 7) << 4)));
    }
    u32 mbuf[4][2];
    #pragma unroll
    for (int h = 0; h < 2; ++h) {
        f32x4 acc[2][4];
        #pragma unroll
        for (int d = 0; d < 2; ++d) {
            const int mi = 2 * h + d;
            const f32x4 bv = *(const f32x4*)(wblob + B3_OFF + (mi * 16 + g * 4) * 4);
            #pragma unroll
            for (int nj = 0; nj < 4; ++nj) acc[d][nj] = bv;
        }
        #pragma unroll
        for (int kt = 0; kt < 2; ++kt) {
            bf16x8 afr[2];
            #pragma unroll
            for (int d = 0; d < 2; ++d)
                afr[d] = *(const bf16x8*)(wblob + W3T_OFF + ((2 * h + d) * 16 + t) * 128 + kt * 64 + (g << 4));
            #pragma unroll
            for (int nj = 0; nj < 4; ++nj) {
                const i32x4 bi = { (int)pk2[2 * kt][nj][0], (int)pk2[2 * kt][nj][1],
                                   (int)pk2[2 * kt + 1][nj][0], (int)pk2[2 * kt + 1][nj][1] };
                const bf16x8 bf = __builtin_bit_cast(bf16x8, bi);
                #pragma unroll
                for (int d = 0; d < 2; ++d)
                    acc[d][nj] = __builtin_amdgcn_mfma_f32_16x16x32_bf16(afr[d], bf, acc[d][nj], 0, 0, 0);
            }
        }
        #pragma unroll
        for (int nj = 0; nj < 4; ++nj) {
            const float f0 = bflo(byw[nj].x), f1 = bfhi(byw[nj].x);
            const float f2 = bflo(byw[nj].y), f3 = bfhi(byw[nj].y);
            u32 pks[2];
            #pragma unroll
            for (int d = 0; d < 2; ++d) {
                const f32x4 a = acc[d][nj];
                float p = fmaf(a[0], f0, fmaf(a[1], f1, fmaf(a[2], f2, a[3] * f3)));
                const float m  = p + __shfl_xor(p, 16, 64);   // full dot
                const float mo = __shfl_xor(m, 32, 64);       // partner channel
                pks[d] = pkbf(m, mo);                          // (2mi, 2mi+1) on g==0
            }
            if (h == 0) {
                mbuf[nj][0] = pks[0]; mbuf[nj][1] = pks[1];
            } else if (g == 0) {
                const int el = nj * 16 + t;
                *(uint4*)(msg + (size_t)(s0 + el) * 8) =
                    make_uint4(mbuf[nj][0], mbuf[nj][1], pks[0], pks[1]);
            }
        }
    }
}

// ---- fused CSR gather + finalize: 8 lanes per node, coalesced uint4 slot reads ----
__global__ __launch_bounds__(256) void gno_gather_out(
    const float* __restrict__ batch, const float* __restrict__ Wlin,
    const u16* __restrict__ msg0, const size_t mstride, const u32* __restrict__ rowptr,
    const u32* __restrict__ cnt, float* __restrict__ out, const int bsel)
{
    const int tid = threadIdx.x;
    const int n = blockIdx.x * 32 + (tid >> 3);
    const int k = tid & 7;
    if (n >= Nn) return;
    const int b = (bsel >= 0) ? bsel : (int)blockIdx.y;
    const u16* msg = msg0 + (size_t)b * mstride;
    const u32 dg = cnt[n];
    const u32 j0 = rowptr[n];
    float acc[8] = {0, 0, 0, 0, 0, 0, 0, 0};
    for (u32 j = j0 + k; j < j0 + dg; j += 8) {
        const uint4 m = *(const uint4*)(msg + (size_t)j * 8);
        acc[0] += bflo(m.x); acc[1] += bfhi(m.x);
        acc[2] += bflo(m.y); acc[3] += bfhi(m.y);
        acc[4] += bflo(m.z); acc[5] += bfhi(m.z);
        acc[6] += bflo(m.w); acc[7] += bfhi(m.w);
    }
    #pragma unroll
    for (int s = 1; s < 8; s <<= 1) {
        #pragma unroll
        for (int c = 0; c < 8; ++c) acc[c] += __shfl_xor(acc[c], s, 64);
    }
    float v = acc[k] * __builtin_amdgcn_rcpf((float)dg + 1.0f);
    const float* br = batch + ((size_t)b * Nn + n) * 8;
    #pragma unroll
    for (int j = 0; j < 8; ++j) v = fmaf(br[j], Wlin[j * FOUT + k], v);
    out[((size_t)b * Nn + n) * 8 + k] = v;   // fully coalesced
}

extern "C" void kernel_launch(void* const* d_in, const int* in_sizes, int n_in,
                              void* d_out, int out_size, void* d_ws, size_t ws_size,
                              hipStream_t stream) {
    const float* batch  = (const float*)d_in[0];
    const float* points = (const float*)d_in[1];
    const int*   neigh  = (const int*)d_in[2];
    const float* W1     = (const float*)d_in[3];
    const float* b1     = (const float*)d_in[4];
    const float* W2     = (const float*)d_in[5];
    const float* b2     = (const float*)d_in[6];
    const float* W3     = (const float*)d_in[7];
    const float* b3     = (const float*)d_in[8];
    const float* Wlin   = (const float*)d_in[9];
    float* out = (float*)d_out;

    unsigned char* ws = (unsigned char*)d_ws;
    u32* cnt    = (u32*)(ws + CNT_OFF);
    u32* rowptr = (u32*)(ws + ROWPTR_OFF);
    u32* bsum   = (u32*)(ws + BSUM_OFF);
    u32* pairs  = (u32*)(ws + PAIRS_OFF);
    u16* rank   = (u16*)(ws + RANK_OFF);     // aliases msg; consumed before msg written
    u16* msg    = (u16*)(ws + MSG_OFF);
    if (ws_size < WS_NEEDED) return;
    const int tier = (ws_size >= WS_4) ? 2 : (ws_size >= WS_CVT) ? 1 : 0;
    u32* pbf = (u32*)(ws + (tier == 2 ? PBF4_OFF : PBF_OFF));
    u16* bbf = (u16*)(ws + (tier == 2 ? BBF4_OFF : BBF_OFF));

    const dim3 b256(256);
    const dim3 gE((En + 255) / 256);
    const dim3 gEdge((En / 64 + 3) / 4);     // 3907
    const dim3 gN((Nn + 255) / 256);         // 196 (<= 256 for scan2)
    const dim3 gGather((Nn + 31) / 32);      // 1563
    const dim3 gCvt((Bn * Nn + 255) / 256);

    hipMemsetAsync(cnt, 0, Nn * sizeof(u32), stream);
    gno_init_weights<<<dim3(41), b256, 0, stream>>>(W1, b1, W2, b2, W3, b3, ws);
    if (tier >= 1)
        gno_cvt<<<gCvt, b256, 0, stream>>>(batch, points, pbf, bbf);
    gno_hist_rank<<<gE, b256, 0, stream>>>(neigh, cnt, rank);
    gno_scan1<<<gN, b256, 0, stream>>>(cnt, rowptr, bsum);
    gno_scan2<<<dim3(1), b256, 0, stream>>>(bsum, (int)gN.x);
    gno_scan3<<<gN, b256, 0, stream>>>(rowptr, bsum);
    gno_slot<<<gE, b256, 0, stream>>>(neigh, rowptr, rank, pairs);

    if (tier == 2) {
        gno_edge_mfma<1><<<dim3(gEdge.x, Bn), b256, 0, stream>>>(
            batch, points, pairs, ws, -1, msg, MSTRIDE, pbf, bbf);
        gno_gather_out<<<dim3(gGather.x, Bn), b256, 0, stream>>>(
            batch, Wlin, msg, MSTRIDE, rowptr, cnt, out, -1);
    } else {
        for (int b = 0; b < Bn; ++b) {
            if (tier == 1)
                gno_edge_mfma<1><<<gEdge, b256, 0, stream>>>(batch, points, pairs, ws, b,
                                                             msg, 0, pbf, bbf);
            else
                gno_edge_mfma<0><<<gEdge, b256, 0, stream>>>(batch, points, pairs, ws, b,
                                                             msg, 0, pbf, bbf);
            gno_gather_out<<<gGather, b256, 0, stream>>>(batch, Wlin, msg, 0, rowptr,
                                                         cnt, out, b);
        }
    }
}